// Round 4
// baseline (1509.661 us; speedup 1.0000x reference)
//
#include <hip/hip_runtime.h>

// PointVoxelCNN fused pipeline for MI355X (gfx950).
// B=8, N=32768, C=Cin=64, R=32, G=32 (2 channels/group).
// Round 4: voxelize rebuilt with duplicated region-insertion (avg 1.95 entries
// per point instead of 8 redundant visits) + batch-4 ILP in vox_accum.
// Conv / point branch unchanged from round 3.

#define RSQRT2 0.70710678118654752440f

typedef float f32x4 __attribute__((ext_vector_type(4)));
typedef __bf16 bf16x8 __attribute__((ext_vector_type(8)));

static __device__ __forceinline__ unsigned short f2bf(float x) {
    union { float f; unsigned u; } v; v.f = x;
    unsigned r = v.u + 0x7FFFu + ((v.u >> 16) & 1u);
    return (unsigned short)(r >> 16);
}
static __device__ __forceinline__ float bf2f(unsigned short b) {
    union { unsigned u; float f; } v; v.u = ((unsigned)b) << 16; return v.f;
}
static __device__ __forceinline__ float leaky(float x) { return x >= 0.f ? x : 0.01f * x; }

static __device__ __forceinline__ void gload_lds16(const void* g, void* l) {
    __builtin_amdgcn_global_load_lds(
        (const __attribute__((address_space(1))) unsigned int*)g,
        (__attribute__((address_space(3))) unsigned int*)l, 16, 0, 0);
}

static __device__ __forceinline__ void corner_setup(float px, float py, float pz,
        int& lx, int& ly, int& lz, float& fx, float& fy, float& fz) {
    float cx = fminf(fmaxf((px + 1.f) * 15.5f, 0.f), 31.f);
    float cy = fminf(fmaxf((py + 1.f) * 15.5f, 0.f), 31.f);
    float cz = fminf(fmaxf((pz + 1.f) * 15.5f, 0.f), 31.f);
    lx = (int)cx; if (lx > 30) lx = 30; fx = cx - (float)lx;
    ly = (int)cy; if (ly > 30) ly = 30; fy = cy - (float)ly;
    lz = (int)cz; if (lz > 30) lz = 30; fz = cz - (float)lz;
}

// ---------------- weight transform: w[O][I][27] f32 -> wt[ko][co][ci] bf16 hi/lo
__global__ __launch_bounds__(256) void wt_transform(const float* __restrict__ w,
                                                    unsigned short* __restrict__ hi,
                                                    unsigned short* __restrict__ lo) {
    int idx = blockIdx.x * 256 + threadIdx.x;    // 27*64*64 = 110592
    int ko = idx >> 12;
    int co = (idx >> 6) & 63;
    int ci = idx & 63;
    float v = w[(co * 64 + ci) * 27 + ko];
    unsigned short h = f2bf(v);
    hi[idx] = h;
    lo[idx] = f2bf(v - bf2f(h));
}

// ---------------- MLP weight transform: w[ci][co] f32 -> wm[L][co][ci] bf16 hi/lo
__global__ __launch_bounds__(256) void mlp_wt(const float* __restrict__ w0,
                                              const float* __restrict__ w1,
                                              const float* __restrict__ w2,
                                              unsigned short* __restrict__ hi,
                                              unsigned short* __restrict__ lo) {
    int idx = blockIdx.x * 256 + threadIdx.x;    // 48*256 = 12288
    int L = idx >> 12, rem = idx & 4095;
    int co = rem >> 6, ci = rem & 63;
    const float* s = (L == 0) ? w0 : (L == 1) ? w1 : w2;
    float v = s[ci * 64 + co];
    unsigned short h = f2bf(v);
    hi[idx] = h;
    lo[idx] = f2bf(v - bf2f(h));
}

// ---------------- voxelize pass 1: count (point -> all touched regions)
// A point with lo-cell (lx,ly,lz) touches region (lx>>2 [+1 if lx%4==3], ...)
__global__ __launch_bounds__(256) void bin_count(const float* __restrict__ pts,
                                                 int* __restrict__ cnt) {
    int p = blockIdx.x * 256 + threadIdx.x;      // 262144
    int lx, ly, lz; float fx, fy, fz;
    corner_setup(pts[p * 3], pts[p * 3 + 1], pts[p * 3 + 2], lx, ly, lz, fx, fy, fz);
    int b = p >> 15;
    int rx = lx >> 2, ry = ly >> 2, rz = lz >> 2;
    int mx = (lx & 3) == 3, my = (ly & 3) == 3, mz = (lz & 3) == 3;
#pragma unroll
    for (int d = 0; d < 8; ++d) {
        int dx = d >> 2, dy = (d >> 1) & 1, dz = d & 1;
        if (dx <= mx && dy <= my && dz <= mz) {
            int bin = (b << 9) | ((rx + dx) << 6) | ((ry + dy) << 3) | (rz + dz);
            atomicAdd(&cnt[bin], 1);
        }
    }
}

// ---------------- voxelize pass 2: exclusive scan of 4096 bins (1 block)
__global__ __launch_bounds__(256) void bin_scan(const int* __restrict__ cnt,
                                                int* __restrict__ start,
                                                int* __restrict__ cursor) {
    __shared__ int part[256];
    int t = threadIdx.x;
    int local[16];
    int s = 0;
#pragma unroll
    for (int i = 0; i < 16; ++i) { local[i] = s; s += cnt[t * 16 + i]; }
    part[t] = s;
    __syncthreads();
    for (int off = 1; off < 256; off <<= 1) {
        int v = (t >= off) ? part[t - off] : 0;
        __syncthreads();
        part[t] += v;
        __syncthreads();
    }
    int base = (t == 0) ? 0 : part[t - 1];
#pragma unroll
    for (int i = 0; i < 16; ++i) {
        int v = base + local[i];
        start[t * 16 + i] = v;
        cursor[t * 16 + i] = v;
    }
    if (t == 255) start[4096] = part[255];
}

// ---------------- voxelize pass 3: scatter point ids into all touched regions
__global__ __launch_bounds__(256) void bin_fill(const float* __restrict__ pts,
                                                int* __restrict__ cursor,
                                                int* __restrict__ idxb) {
    int p = blockIdx.x * 256 + threadIdx.x;
    int lx, ly, lz; float fx, fy, fz;
    corner_setup(pts[p * 3], pts[p * 3 + 1], pts[p * 3 + 2], lx, ly, lz, fx, fy, fz);
    int b = p >> 15;
    int rx = lx >> 2, ry = ly >> 2, rz = lz >> 2;
    int mx = (lx & 3) == 3, my = (ly & 3) == 3, mz = (lz & 3) == 3;
#pragma unroll
    for (int d = 0; d < 8; ++d) {
        int dx = d >> 2, dy = (d >> 1) & 1, dz = d & 1;
        if (dx <= mx && dy <= my && dz <= mz) {
            int bin = (b << 9) | ((rx + dx) << 6) | ((ry + dy) << 3) | (rz + dz);
            int slot = atomicAdd(&cursor[bin], 1);
            idxb[slot] = p;
        }
    }
}

// ---------------- voxelize pass 4: exclusive-list accumulate + normalize + GN1 stats
// one block per 4x4x4 region; iterates ONLY its own (pre-filtered) point list.
__global__ __launch_bounds__(256) void vox_accum(const float* __restrict__ pts,
                                                 const float* __restrict__ feat,
                                                 const int* __restrict__ start,
                                                 const int* __restrict__ idxb,
                                                 float* __restrict__ vox,
                                                 float* __restrict__ chsum) {
    __shared__ float acc[4096];      // [cell 64][ch 64]
    __shared__ float cw[64];
    __shared__ float rs[256], rq[256];
    int tid = threadIdx.x, lane = tid & 63, wv = tid >> 6;
    int gid = blockIdx.x;            // 4096 = b*512 + r3
    int b = gid >> 9, r3 = gid & 511;
    int rx = r3 >> 6, ry = (r3 >> 3) & 7, rz = r3 & 7;
    int cx0 = rx << 2, cy0 = ry << 2, cz0 = rz << 2;
    for (int i = tid; i < 4096; i += 256) acc[i] = 0.f;
    if (tid < 64) cw[tid] = 0.f;
    __syncthreads();

    int s0 = start[gid], s1 = start[gid + 1];
    // batch-4 per wave: 4 independent load chains in flight
    for (int base = s0 + (wv << 2); base < s1; base += 16) {
        int n = s1 - base; if (n > 4) n = 4;
        int pid[4];
        float px[4], py[4], pz[4], fv[4];
#pragma unroll
        for (int j = 0; j < 4; ++j) {
            pid[j] = (j < n) ? idxb[base + j] : -1;
        }
#pragma unroll
        for (int j = 0; j < 4; ++j) {
            if (pid[j] >= 0) {
                px[j] = pts[pid[j] * 3];
                py[j] = pts[pid[j] * 3 + 1];
                pz[j] = pts[pid[j] * 3 + 2];
                fv[j] = feat[((size_t)pid[j] << 6) + lane];
            }
        }
#pragma unroll
        for (int j = 0; j < 4; ++j) {
            if (pid[j] < 0) continue;
            int lx, ly, lz; float fx, fy, fz;
            corner_setup(px[j], py[j], pz[j], lx, ly, lz, fx, fy, fz);
#pragma unroll
            for (int cr = 0; cr < 8; ++cr) {
                int ux = lx + (cr >> 2) - cx0;
                int uy = ly + ((cr >> 1) & 1) - cy0;
                int uz = lz + (cr & 1) - cz0;
                if (((unsigned)ux < 4u) && ((unsigned)uy < 4u) && ((unsigned)uz < 4u)) {
                    float w = ((cr & 4) ? fx : 1.f - fx) * ((cr & 2) ? fy : 1.f - fy)
                            * ((cr & 1) ? fz : 1.f - fz);
                    int cl = (ux << 4) | (uy << 2) | uz;
                    atomicAdd(&acc[(cl << 6) | lane], w * fv[j]);
                }
            }
            // corner-weight totals: one DS op, 8 lanes in parallel
            if (lane < 8) {
                int di = (lane >> 2) & 1, dj = (lane >> 1) & 1, dkk = lane & 1;
                int ux = lx + di - cx0, uy = ly + dj - cy0, uz = lz + dkk - cz0;
                if (((unsigned)ux < 4u) && ((unsigned)uy < 4u) && ((unsigned)uz < 4u)) {
                    float w = (di ? fx : 1.f - fx) * (dj ? fy : 1.f - fy)
                            * (dkk ? fz : 1.f - fz);
                    atomicAdd(&cw[(ux << 4) | (uy << 2) | uz], w);
                }
            }
        }
    }
    __syncthreads();
    // normalize + write + per-channel partial sums
    float s = 0.f, q = 0.f;
    for (int c = wv; c < 64; c += 4) {
        float v = acc[(c << 6) | lane] / fmaxf(cw[c], 1e-8f);
        int cxx = cx0 + (c >> 4), cyy = cy0 + ((c >> 2) & 3), czz = cz0 + (c & 3);
        size_t flat = ((size_t)(b << 15)) + (size_t)((cxx << 10) | (cyy << 5) | czz);
        vox[(flat << 6) + lane] = v;
        s += v; q += v * v;
    }
    rs[tid] = s; rq[tid] = q;
    __syncthreads();
    if (tid < 64) {
        s = rs[tid] + rs[tid + 64] + rs[tid + 128] + rs[tid + 192];
        q = rq[tid] + rq[tid + 64] + rq[tid + 128] + rq[tid + 192];
        atomicAdd(&chsum[((b << 6) + tid) * 2], s);
        atomicAdd(&chsum[((b << 6) + tid) * 2 + 1], q);
    }
}

// ---------------- per-channel partial sums for GN2 (reads conv1 output)
__global__ __launch_bounds__(256) void norm_stats(const float* __restrict__ src,
                                                  float* __restrict__ chsum) {
    __shared__ float rs[256], rq[256];
    int b = blockIdx.y;
    int tid = threadIdx.x;
    int c = tid & 63, rsub = tid >> 6;
    size_t rowb = ((size_t)b << 15) + (size_t)blockIdx.x * 256;
    float s = 0.f, q = 0.f;
    for (int i = 0; i < 64; ++i) {
        size_t idx = ((rowb + rsub + i * 4) << 6) + c;
        float v = src[idx];
        s += v; q += v * v;
    }
    rs[tid] = s; rq[tid] = q;
    __syncthreads();
    if (tid < 64) {
        s = rs[tid] + rs[tid + 64] + rs[tid + 128] + rs[tid + 192];
        q = rq[tid] + rq[tid + 64] + rq[tid + 128] + rq[tid + 192];
        atomicAdd(&chsum[((b << 6) + tid) * 2], s);
        atomicAdd(&chsum[((b << 6) + tid) * 2 + 1], q);
    }
}

// ---------------- finalize GN stats: chsum[b][64][2] -> musr[b][32][2] (mu, rstd)
__global__ void gn_finalize(const float* __restrict__ chsum, float* __restrict__ musr) {
    int t = threadIdx.x;              // 256 = 8 b * 32 g
    int b = t >> 5, g = t & 31;
    float s = chsum[((b << 6) + 2 * g) * 2] + chsum[((b << 6) + 2 * g + 1) * 2];
    float q = chsum[((b << 6) + 2 * g) * 2 + 1] + chsum[((b << 6) + 2 * g + 1) * 2 + 1];
    float mu = s * (1.f / 65536.f);
    float var = q * (1.f / 65536.f) - mu * mu;
    musr[t * 2] = mu;
    musr[t * 2 + 1] = rsqrtf(var + 1e-5f);
}

// ---------------- GN apply + leaky -> bf16 hi/lo activation planes
__global__ __launch_bounds__(256) void gn_apply(const float* __restrict__ src,
                                                const float* __restrict__ musr,
                                                const float* __restrict__ gamma,
                                                const float* __restrict__ beta,
                                                unsigned short* __restrict__ hi,
                                                unsigned short* __restrict__ lo) {
    int i4 = blockIdx.x * 256 + threadIdx.x;     // B*R3*16
    int row = i4 >> 4;
    int b = row >> 15;
    int c0 = (i4 & 15) << 2;
    const float4 x = *(const float4*)(src + ((size_t)i4 << 2));
    float xs[4] = {x.x, x.y, x.z, x.w};
    unsigned short hs[4], ls[4];
#pragma unroll
    for (int j = 0; j < 4; ++j) {
        int c = c0 + j;
        int g = c >> 1;
        float mu = musr[((b << 5) + g) * 2];
        float rstd = musr[((b << 5) + g) * 2 + 1];
        float y = (xs[j] - mu) * rstd * gamma[c] + beta[c];
        y = leaky(y);
        hs[j] = f2bf(y);
        ls[j] = f2bf(y - bf2f(hs[j]));
    }
    ushort4 H; H.x = hs[0]; H.y = hs[1]; H.z = hs[2]; H.w = hs[3];
    ushort4 L; L.x = ls[0]; L.y = ls[1]; L.z = ls[2]; L.w = ls[3];
    *(ushort4*)(hi + ((size_t)i4 << 2)) = H;
    *(ushort4*)(lo + ((size_t)i4 << 2)) = L;
}

// ---------------- conv3d 3x3x3 SAME, 64->64ch, bf16 hi/lo 3-term MFMA
__global__ __launch_bounds__(256, 2) void conv3d_k(
        const unsigned short* __restrict__ Ah, const unsigned short* __restrict__ Al,
        const unsigned short* __restrict__ Wh, const unsigned short* __restrict__ Wl,
        const float* __restrict__ bias, const float* __restrict__ skip,
        float* __restrict__ out, const char* __restrict__ zp) {
    __shared__ __align__(16) unsigned short sAh[16384], sAl[16384], sWh[4096], sWl[4096]; // 80KB
    int tid = threadIdx.x;
    int lane = tid & 63, wave = tid >> 6;
    int wg = blockIdx.x;                       // 1024; XCD-swizzle: one batch per XCD
    int sw = (wg & 7) * 128 + (wg >> 3);
    int b = sw >> 7, t = sw & 127;
    int w0 = (t & 3) << 3, h0 = ((t >> 2) & 3) << 3, d0 = (t >> 4) << 2;

    f32x4 acc[4][4] = {};
    const char* AhB = (const char*)Ah;
    const char* AlB = (const char*)Al;
    const char* WhB = (const char*)Wh;
    const char* WlB = (const char*)Wl;

    for (int ko = 0; ko < 27; ++ko) {
        int di = ko / 9, rem = ko - di * 9, dj = rem / 3, dk = rem - dj * 3;
        __syncthreads();                       // all waves done reading previous tap
        // ---- stage A hi+lo
#pragma unroll
        for (int i = 0; i < 8; ++i) {
            int X = (i * 256 + tid) << 4;      // linear LDS byte
            int row = X >> 7;                  // voxel row (128B rows)
            int gran = ((X >> 4) & 7) ^ (row & 7);   // source pre-swizzle
            int d = row >> 6, h = (row >> 3) & 7, w = row & 7;
            int gd = d0 + d + di - 1, gh = h0 + h + dj - 1, gw = w0 + w + dk - 1;
            bool ok = ((unsigned)gd < 32u) & ((unsigned)gh < 32u) & ((unsigned)gw < 32u);
            size_t goff = ((((size_t)(b << 15)) +
                            (size_t)((gd << 10) + (gh << 5) + gw)) << 7) + (gran << 4);
            const char* gph = ok ? (AhB + goff) : (zp + (gran << 4));
            const char* gpl = ok ? (AlB + goff) : (zp + (gran << 4));
            int ldsoff = (i * 256 + (wave << 6)) << 4;   // wave-uniform base
            gload_lds16(gph, (char*)sAh + ldsoff);
            gload_lds16(gpl, (char*)sAl + ldsoff);
        }
        // ---- stage W hi+lo
#pragma unroll
        for (int i = 0; i < 2; ++i) {
            int X = (i * 256 + tid) << 4;
            int row = X >> 7;                  // cout row
            int gran = ((X >> 4) & 7) ^ (row & 7);
            size_t goff = ((size_t)((ko << 12) + (row << 6) + (gran << 3))) << 1;
            int ldsoff = (i * 256 + (wave << 6)) << 4;
            gload_lds16(WhB + goff, (char*)sWh + ldsoff);
            gload_lds16(WlB + goff, (char*)sWl + ldsoff);
        }
        __syncthreads();
        // ---- compute
#pragma unroll
        for (int kh = 0; kh < 2; ++kh) {
            bf16x8 a_h[4], a_l[4], b_h[4], b_l[4];
#pragma unroll
            for (int mf = 0; mf < 4; ++mf) {
                int arow = (wave << 6) + (mf << 4) + (lane & 15);
                int byteoff = (arow << 7) | ((((kh << 2) | (lane >> 4)) ^ (arow & 7)) << 4);
                a_h[mf] = *(const bf16x8*)((const char*)sAh + byteoff);
                a_l[mf] = *(const bf16x8*)((const char*)sAl + byteoff);
            }
#pragma unroll
            for (int nf = 0; nf < 4; ++nf) {
                int brow = (nf << 4) + (lane & 15);
                int byteoff = (brow << 7) | ((((kh << 2) | (lane >> 4)) ^ (brow & 7)) << 4);
                b_h[nf] = *(const bf16x8*)((const char*)sWh + byteoff);
                b_l[nf] = *(const bf16x8*)((const char*)sWl + byteoff);
            }
#pragma unroll
            for (int mf = 0; mf < 4; ++mf)
#pragma unroll
                for (int nf = 0; nf < 4; ++nf) {
                    acc[mf][nf] = __builtin_amdgcn_mfma_f32_16x16x32_bf16(a_h[mf], b_h[nf], acc[mf][nf], 0, 0, 0);
                    acc[mf][nf] = __builtin_amdgcn_mfma_f32_16x16x32_bf16(a_h[mf], b_l[nf], acc[mf][nf], 0, 0, 0);
                    acc[mf][nf] = __builtin_amdgcn_mfma_f32_16x16x32_bf16(a_l[mf], b_h[nf], acc[mf][nf], 0, 0, 0);
                }
        }
    }
    // ---- epilogue
#pragma unroll
    for (int mf = 0; mf < 4; ++mf) {
#pragma unroll
        for (int nf = 0; nf < 4; ++nf) {
            int co = (nf << 4) + (lane & 15);
            float bv = bias[co];
#pragma unroll
            for (int r = 0; r < 4; ++r) {
                int vrow = (wave << 6) + (mf << 4) + ((lane >> 4) << 2) + r;
                int d = vrow >> 6, h = (vrow >> 3) & 7, w = vrow & 7;
                size_t flat = ((size_t)(b << 15)) +
                              (size_t)(((d0 + d) << 10) + ((h0 + h) << 5) + (w0 + w));
                size_t oi = (flat << 6) + co;
                float v = acc[mf][nf][r] + bv;
                if (skip) v = (v + skip[oi]) * RSQRT2;
                out[oi] = v;
            }
        }
    }
}

// ---------------- point MLP: 3x (64x64 GEMM) via MFMA bf16 hi/lo, 256 pts/block
__global__ __launch_bounds__(256, 2) void point_mlp(
        const float* __restrict__ feat,
        const unsigned short* __restrict__ Mh, const unsigned short* __restrict__ Ml,
        const float* __restrict__ b0, const float* __restrict__ b1,
        const float* __restrict__ b2, float* __restrict__ pout) {
    __shared__ __align__(16) unsigned short sAh[16384], sAl[16384], sWh[4096], sWl[4096]; // 80KB
    int tid = threadIdx.x, lane = tid & 63, wave = tid >> 6;
    size_t pbase = (size_t)blockIdx.x << 8;

    // stage A: feat fp32 -> bf16 hi/lo, swizzled (rows = points, 128B rows)
    const float4* f4 = (const float4*)(feat + (pbase << 6));
#pragma unroll
    for (int j = 0; j < 16; ++j) {
        int fidx = j * 256 + tid;
        float4 v = f4[fidx];
        float vv[4] = {v.x, v.y, v.z, v.w};
        unsigned short hh[4], ll[4];
#pragma unroll
        for (int k = 0; k < 4; ++k) { hh[k] = f2bf(vv[k]); ll[k] = f2bf(vv[k] - bf2f(hh[k])); }
        ushort4 H; H.x = hh[0]; H.y = hh[1]; H.z = hh[2]; H.w = hh[3];
        ushort4 Lo; Lo.x = ll[0]; Lo.y = ll[1]; Lo.z = ll[2]; Lo.w = ll[3];
        int Xb = fidx << 3;                    // byte offset in bf16 A-plane
        int row = Xb >> 7;
        int dest = (row << 7) | ((((Xb >> 4) & 7) ^ (row & 7)) << 4) | (Xb & 8);
        *(ushort4*)((char*)sAh + dest) = H;
        *(ushort4*)((char*)sAl + dest) = Lo;
    }

    f32x4 f0[4][4];
#pragma unroll
    for (int L = 0; L < 3; ++L) {
        __syncthreads();                       // A/act writes visible; sW free
        // stage W layer L (pre-swizzled source, linear LDS dest)
#pragma unroll
        for (int i = 0; i < 2; ++i) {
            int X = (i * 256 + tid) << 4;
            int row = X >> 7;
            int gran = ((X >> 4) & 7) ^ (row & 7);
            size_t goff = ((size_t)((L << 12) + (row << 6) + (gran << 3))) << 1;
            int ldsoff = (i * 256 + (wave << 6)) << 4;
            gload_lds16((const char*)Mh + goff, (char*)sWh + ldsoff);
            gload_lds16((const char*)Ml + goff, (char*)sWl + ldsoff);
        }
        __syncthreads();
        f32x4 acc[4][4] = {};
#pragma unroll
        for (int kh = 0; kh < 2; ++kh) {
            bf16x8 a_h[4], a_l[4], b_h[4], b_l[4];
#pragma unroll
            for (int mf = 0; mf < 4; ++mf) {
                int arow = (wave << 6) + (mf << 4) + (lane & 15);
                int byteoff = (arow << 7) | ((((kh << 2) | (lane >> 4)) ^ (arow & 7)) << 4);
                a_h[mf] = *(const bf16x8*)((const char*)sAh + byteoff);
                a_l[mf] = *(const bf16x8*)((const char*)sAl + byteoff);
            }
#pragma unroll
            for (int nf = 0; nf < 4; ++nf) {
                int brow = (nf << 4) + (lane & 15);
                int byteoff = (brow << 7) | ((((kh << 2) | (lane >> 4)) ^ (brow & 7)) << 4);
                b_h[nf] = *(const bf16x8*)((const char*)sWh + byteoff);
                b_l[nf] = *(const bf16x8*)((const char*)sWl + byteoff);
            }
#pragma unroll
            for (int mf = 0; mf < 4; ++mf)
#pragma unroll
                for (int nf = 0; nf < 4; ++nf) {
                    acc[mf][nf] = __builtin_amdgcn_mfma_f32_16x16x32_bf16(a_h[mf], b_h[nf], acc[mf][nf], 0, 0, 0);
                    acc[mf][nf] = __builtin_amdgcn_mfma_f32_16x16x32_bf16(a_h[mf], b_l[nf], acc[mf][nf], 0, 0, 0);
                    acc[mf][nf] = __builtin_amdgcn_mfma_f32_16x16x32_bf16(a_l[mf], b_h[nf], acc[mf][nf], 0, 0, 0);
                }
        }
        const float* bp = (L == 0) ? b0 : (L == 1) ? b1 : b2;
        if (L < 2) {
            __syncthreads();                   // all waves done reading sA this layer
#pragma unroll
            for (int nf = 0; nf < 4; ++nf) {
                int col = (nf << 4) + (lane & 15);
                float bv = bp[col];
#pragma unroll
                for (int mf = 0; mf < 4; ++mf)
#pragma unroll
                    for (int r = 0; r < 4; ++r) {
                        float v = acc[mf][nf][r] + bv;
                        if (L == 0) f0[mf][nf][r] = v;
                        float a = leaky(v);
                        unsigned short h = f2bf(a);
                        unsigned short l = f2bf(a - bf2f(h));
                        int row = (wave << 6) + (mf << 4) + ((lane >> 4) << 2) + r;
                        int dest = (row << 7) | (((col >> 3) ^ (row & 7)) << 4) | ((col << 1) & 15);
                        *(unsigned short*)((char*)sAh + dest) = h;
                        *(unsigned short*)((char*)sAl + dest) = l;
                    }
            }
        } else {
#pragma unroll
            for (int nf = 0; nf < 4; ++nf) {
                int col = (nf << 4) + (lane & 15);
                float bv = bp[col];
#pragma unroll
                for (int mf = 0; mf < 4; ++mf)
#pragma unroll
                    for (int r = 0; r < 4; ++r) {
                        int row = (wave << 6) + (mf << 4) + ((lane >> 4) << 2) + r;
                        float v = (acc[mf][nf][r] + bv + f0[mf][nf][r]) * RSQRT2;
                        pout[((pbase + row) << 6) + col] = v;
                    }
            }
        }
    }
}

// ---------------- devoxelize gather + final combine (lean, high-occupancy)
__global__ __launch_bounds__(256, 8) void devox_combine(
        const float* __restrict__ pts, const float* __restrict__ pmlp,
        const float* __restrict__ grid, float* __restrict__ out) {
    __shared__ int   sFl[64][8];
    __shared__ float sWt[64][8];
    int tid = threadIdx.x;
    size_t pbase = (size_t)blockIdx.x << 6;
    int b = (int)(pbase >> 15);
    if (tid < 64) {
        const float* P = pts + (pbase + tid) * 3;
        int lx, ly, lz; float fx, fy, fz;
        corner_setup(P[0], P[1], P[2], lx, ly, lz, fx, fy, fz);
        int base3 = (lx << 10) + (ly << 5) + lz;
#pragma unroll
        for (int cr = 0; cr < 8; ++cr) {
            sFl[tid][cr] = base3 + (cr >> 2) * 1024 + ((cr >> 1) & 1) * 32 + (cr & 1);
            sWt[tid][cr] = ((cr & 4) ? fx : 1.f - fx) * ((cr & 2) ? fy : 1.f - fy)
                         * ((cr & 1) ? fz : 1.f - fz);
        }
    }
    __syncthreads();
    int c = tid & 63, wv = tid >> 6;
    const float* gb = grid + (((size_t)b) << 21);
#pragma unroll 4
    for (int i = 0; i < 16; ++i) {
        int p = (wv << 4) + i;                 // whole wave shares p -> LDS broadcast
        float dev = 0.f;
#pragma unroll
        for (int cr = 0; cr < 8; ++cr)
            dev += sWt[p][cr] * gb[(((size_t)sFl[p][cr]) << 6) + c];
        size_t oi = ((pbase + p) << 6) + c;
        out[oi] = (pmlp[oi] + dev) * RSQRT2;
    }
}

// ---------------- workspace layout (bytes)
constexpr size_t OFF_VOX  = 0;                           // f32 [8][32768][64] (normalized)
constexpr size_t OFF_GBUF = 67108864;                    // f32 [8][32768][64]
constexpr size_t OFF_AHI  = OFF_GBUF + 67108864;         // bf16 staging; later pmlp f32 (64MB)
constexpr size_t OFF_ALO  = OFF_AHI + 33554432;
constexpr size_t OFF_W1H  = OFF_ALO + 33554432;          // bf16 [27][64][64]
constexpr size_t OFF_W1L  = OFF_W1H + 262144;
constexpr size_t OFF_W2H  = OFF_W1L + 262144;
constexpr size_t OFF_W2L  = OFF_W2H + 262144;
constexpr size_t OFF_CS1  = OFF_W2L + 262144;            // f32 [8][64][2]
constexpr size_t OFF_CS2  = OFF_CS1 + 4096;
constexpr size_t OFF_MS1  = OFF_CS2 + 4096;              // f32 [8][32][2]
constexpr size_t OFF_MS2  = OFF_MS1 + 2048;
constexpr size_t OFF_BCNT = OFF_MS2 + 2048;              // int [4096]
constexpr size_t OFF_BSTA = OFF_BCNT + 16384;            // int [4097]
constexpr size_t OFF_BCUR = OFF_BSTA + 20480;            // int [4096]
constexpr size_t OFF_IDX  = OFF_BCUR + 16384;            // int [<=2097152] (8x worst case)
constexpr size_t OFF_ZP   = OFF_IDX + 8388608;           // 256B zeros
constexpr size_t OFF_MWH  = OFF_ZP + 256;                // bf16 [3][64][64]
constexpr size_t OFF_MWL  = OFF_MWH + 24576;
constexpr size_t OFF_END  = OFF_MWL + 24576;

extern "C" void kernel_launch(void* const* d_in, const int* in_sizes, int n_in,
                              void* d_out, int out_size, void* d_ws, size_t ws_size,
                              hipStream_t stream) {
    const float* points = (const float*)d_in[0];
    const float* feat   = (const float*)d_in[1];
    const float* w_pi = (const float*)d_in[2];
    const float* b_pi = (const float*)d_in[3];
    const float* w_p1 = (const float*)d_in[4];
    const float* b_p1 = (const float*)d_in[5];
    const float* w_p2 = (const float*)d_in[6];
    const float* b_p2 = (const float*)d_in[7];
    const float* g1   = (const float*)d_in[8];
    const float* be1  = (const float*)d_in[9];
    const float* w_c1 = (const float*)d_in[10];
    const float* b_c1 = (const float*)d_in[11];
    const float* g2   = (const float*)d_in[12];
    const float* be2  = (const float*)d_in[13];
    const float* w_c2 = (const float*)d_in[14];
    const float* b_c2 = (const float*)d_in[15];

    char* ws = (char*)d_ws;
    float* vox  = (float*)(ws + OFF_VOX);
    float* gbuf = (float*)(ws + OFF_GBUF);
    unsigned short* ahi = (unsigned short*)(ws + OFF_AHI);
    unsigned short* alo = (unsigned short*)(ws + OFF_ALO);
    float* pmlp = (float*)(ws + OFF_AHI);      // reuses ahi+alo after conv2
    unsigned short* w1h = (unsigned short*)(ws + OFF_W1H);
    unsigned short* w1l = (unsigned short*)(ws + OFF_W1L);
    unsigned short* w2h = (unsigned short*)(ws + OFF_W2H);
    unsigned short* w2l = (unsigned short*)(ws + OFF_W2L);
    float* cs1 = (float*)(ws + OFF_CS1);
    float* cs2 = (float*)(ws + OFF_CS2);
    float* ms1 = (float*)(ws + OFF_MS1);
    float* ms2 = (float*)(ws + OFF_MS2);
    int* bcnt = (int*)(ws + OFF_BCNT);
    int* bsta = (int*)(ws + OFF_BSTA);
    int* bcur = (int*)(ws + OFF_BCUR);
    int* idxb = (int*)(ws + OFF_IDX);
    char* zp  = ws + OFF_ZP;
    unsigned short* mwh = (unsigned short*)(ws + OFF_MWH);
    unsigned short* mwl = (unsigned short*)(ws + OFF_MWL);

    hipMemsetAsync(ws + OFF_CS1, 0, 12288, stream);
    hipMemsetAsync(ws + OFF_BCNT, 0, 16384, stream);
    hipMemsetAsync(ws + OFF_ZP, 0, 256, stream);

    wt_transform<<<432, 256, 0, stream>>>(w_c1, w1h, w1l);
    wt_transform<<<432, 256, 0, stream>>>(w_c2, w2h, w2l);
    mlp_wt<<<48, 256, 0, stream>>>(w_pi, w_p1, w_p2, mwh, mwl);

    bin_count<<<1024, 256, 0, stream>>>(points, bcnt);
    bin_scan<<<1, 256, 0, stream>>>(bcnt, bsta, bcur);
    bin_fill<<<1024, 256, 0, stream>>>(points, bcur, idxb);
    vox_accum<<<4096, 256, 0, stream>>>(points, feat, bsta, idxb, vox, cs1);

    gn_finalize<<<1, 256, 0, stream>>>(cs1, ms1);
    gn_apply<<<16384, 256, 0, stream>>>(vox, ms1, g1, be1, ahi, alo);
    conv3d_k<<<1024, 256, 0, stream>>>(ahi, alo, w1h, w1l, b_c1, nullptr, gbuf, zp);

    norm_stats<<<dim3(128, 8), 256, 0, stream>>>(gbuf, cs2);
    gn_finalize<<<1, 256, 0, stream>>>(cs2, ms2);
    gn_apply<<<16384, 256, 0, stream>>>(gbuf, ms2, g2, be2, ahi, alo);
    conv3d_k<<<1024, 256, 0, stream>>>(ahi, alo, w2h, w2l, b_c2, vox, gbuf, zp);

    point_mlp<<<1024, 256, 0, stream>>>(feat, mwh, mwl, b_pi, b_p1, b_p2, pmlp);
    devox_combine<<<4096, 256, 0, stream>>>(points, pmlp, gbuf, (float*)d_out);
}

// Round 5
// 1051.915 us; speedup vs baseline: 1.4352x; 1.4352x over previous
//
#include <hip/hip_runtime.h>

// PointVoxelCNN fused pipeline for MI355X (gfx950).
// B=8, N=32768, C=Cin=64, R=32, G=32 (2 channels/group).
// Round 5: vox_accum rebuilt atomic-free: per-thread register accumulation
// (cell=lane, 16 channels per wave, static indexing), branch-free cndmask
// weights, rotation-swizzled LDS transpose epilogue. The 2.1M predicated LDS
// atomics (the round-3/4 810us serializer) are gone entirely.
// Conv / point branch / binning unchanged from round 4.

#define RSQRT2 0.70710678118654752440f

typedef float f32x4 __attribute__((ext_vector_type(4)));
typedef __bf16 bf16x8 __attribute__((ext_vector_type(8)));

static __device__ __forceinline__ unsigned short f2bf(float x) {
    union { float f; unsigned u; } v; v.f = x;
    unsigned r = v.u + 0x7FFFu + ((v.u >> 16) & 1u);
    return (unsigned short)(r >> 16);
}
static __device__ __forceinline__ float bf2f(unsigned short b) {
    union { unsigned u; float f; } v; v.u = ((unsigned)b) << 16; return v.f;
}
static __device__ __forceinline__ float leaky(float x) { return x >= 0.f ? x : 0.01f * x; }

static __device__ __forceinline__ void gload_lds16(const void* g, void* l) {
    __builtin_amdgcn_global_load_lds(
        (const __attribute__((address_space(1))) unsigned int*)g,
        (__attribute__((address_space(3))) unsigned int*)l, 16, 0, 0);
}

static __device__ __forceinline__ void corner_setup(float px, float py, float pz,
        int& lx, int& ly, int& lz, float& fx, float& fy, float& fz) {
    float cx = fminf(fmaxf((px + 1.f) * 15.5f, 0.f), 31.f);
    float cy = fminf(fmaxf((py + 1.f) * 15.5f, 0.f), 31.f);
    float cz = fminf(fmaxf((pz + 1.f) * 15.5f, 0.f), 31.f);
    lx = (int)cx; if (lx > 30) lx = 30; fx = cx - (float)lx;
    ly = (int)cy; if (ly > 30) ly = 30; fy = cy - (float)ly;
    lz = (int)cz; if (lz > 30) lz = 30; fz = cz - (float)lz;
}

// ---------------- weight transform: w[O][I][27] f32 -> wt[ko][co][ci] bf16 hi/lo
__global__ __launch_bounds__(256) void wt_transform(const float* __restrict__ w,
                                                    unsigned short* __restrict__ hi,
                                                    unsigned short* __restrict__ lo) {
    int idx = blockIdx.x * 256 + threadIdx.x;    // 27*64*64 = 110592
    int ko = idx >> 12;
    int co = (idx >> 6) & 63;
    int ci = idx & 63;
    float v = w[(co * 64 + ci) * 27 + ko];
    unsigned short h = f2bf(v);
    hi[idx] = h;
    lo[idx] = f2bf(v - bf2f(h));
}

// ---------------- MLP weight transform: w[ci][co] f32 -> wm[L][co][ci] bf16 hi/lo
__global__ __launch_bounds__(256) void mlp_wt(const float* __restrict__ w0,
                                              const float* __restrict__ w1,
                                              const float* __restrict__ w2,
                                              unsigned short* __restrict__ hi,
                                              unsigned short* __restrict__ lo) {
    int idx = blockIdx.x * 256 + threadIdx.x;    // 48*256 = 12288
    int L = idx >> 12, rem = idx & 4095;
    int co = rem >> 6, ci = rem & 63;
    const float* s = (L == 0) ? w0 : (L == 1) ? w1 : w2;
    float v = s[ci * 64 + co];
    unsigned short h = f2bf(v);
    hi[idx] = h;
    lo[idx] = f2bf(v - bf2f(h));
}

// ---------------- voxelize pass 1: count (point -> all touched regions)
__global__ __launch_bounds__(256) void bin_count(const float* __restrict__ pts,
                                                 int* __restrict__ cnt) {
    int p = blockIdx.x * 256 + threadIdx.x;      // 262144
    int lx, ly, lz; float fx, fy, fz;
    corner_setup(pts[p * 3], pts[p * 3 + 1], pts[p * 3 + 2], lx, ly, lz, fx, fy, fz);
    int b = p >> 15;
    int rx = lx >> 2, ry = ly >> 2, rz = lz >> 2;
    int mx = (lx & 3) == 3, my = (ly & 3) == 3, mz = (lz & 3) == 3;
#pragma unroll
    for (int d = 0; d < 8; ++d) {
        int dx = d >> 2, dy = (d >> 1) & 1, dz = d & 1;
        if (dx <= mx && dy <= my && dz <= mz) {
            int bin = (b << 9) | ((rx + dx) << 6) | ((ry + dy) << 3) | (rz + dz);
            atomicAdd(&cnt[bin], 1);
        }
    }
}

// ---------------- voxelize pass 2: exclusive scan of 4096 bins (1 block)
__global__ __launch_bounds__(256) void bin_scan(const int* __restrict__ cnt,
                                                int* __restrict__ start,
                                                int* __restrict__ cursor) {
    __shared__ int part[256];
    int t = threadIdx.x;
    int local[16];
    int s = 0;
#pragma unroll
    for (int i = 0; i < 16; ++i) { local[i] = s; s += cnt[t * 16 + i]; }
    part[t] = s;
    __syncthreads();
    for (int off = 1; off < 256; off <<= 1) {
        int v = (t >= off) ? part[t - off] : 0;
        __syncthreads();
        part[t] += v;
        __syncthreads();
    }
    int base = (t == 0) ? 0 : part[t - 1];
#pragma unroll
    for (int i = 0; i < 16; ++i) {
        int v = base + local[i];
        start[t * 16 + i] = v;
        cursor[t * 16 + i] = v;
    }
    if (t == 255) start[4096] = part[255];
}

// ---------------- voxelize pass 3: scatter point ids into all touched regions
__global__ __launch_bounds__(256) void bin_fill(const float* __restrict__ pts,
                                                int* __restrict__ cursor,
                                                int* __restrict__ idxb) {
    int p = blockIdx.x * 256 + threadIdx.x;
    int lx, ly, lz; float fx, fy, fz;
    corner_setup(pts[p * 3], pts[p * 3 + 1], pts[p * 3 + 2], lx, ly, lz, fx, fy, fz);
    int b = p >> 15;
    int rx = lx >> 2, ry = ly >> 2, rz = lz >> 2;
    int mx = (lx & 3) == 3, my = (ly & 3) == 3, mz = (lz & 3) == 3;
#pragma unroll
    for (int d = 0; d < 8; ++d) {
        int dx = d >> 2, dy = (d >> 1) & 1, dz = d & 1;
        if (dx <= mx && dy <= my && dz <= mz) {
            int bin = (b << 9) | ((rx + dx) << 6) | ((ry + dy) << 3) | (rz + dz);
            int slot = atomicAdd(&cursor[bin], 1);
            idxb[slot] = p;
        }
    }
}

// ---------------- voxelize pass 4: register accumulate (atomic-free, branch-free)
// block = 4x4x4 region. thread (wv,lane): cell = lane, channels = wv*16..wv*16+15.
// Each wave iterates the full region list; per visit each lane computes its
// cell's trilinear weight via cndmask selects and does 16 static-indexed FMAs.
__global__ __launch_bounds__(256) void vox_accum(const float* __restrict__ pts,
                                                 const float* __restrict__ feat,
                                                 const int* __restrict__ start,
                                                 const int* __restrict__ idxb,
                                                 float* __restrict__ vox,
                                                 float* __restrict__ chsum) {
    __shared__ float accs[4096];     // [cell][ch] rotation-swizzled
    __shared__ float cws[64];
    __shared__ float rs[256], rq[256];
    int tid = threadIdx.x, lane = tid & 63, wv = tid >> 6;
    int gid = blockIdx.x;            // 4096 = b*512 + r3
    int b = gid >> 9, r3 = gid & 511;
    int rx = r3 >> 6, ry = (r3 >> 3) & 7, rz = r3 & 7;
    int cx0 = rx << 2, cy0 = ry << 2, cz0 = rz << 2;
    int cx = lane >> 4, cy = (lane >> 2) & 3, cz = lane & 3;   // this lane's cell
    int ch0 = wv << 4;

    float acc[16] = {};
    float cwr = 0.f;

    int s0 = start[gid], s1 = start[gid + 1];
    for (int base = s0; base < s1; base += 2) {
        int p0 = idxb[base];
        bool has1 = (base + 1) < s1;
        int p1 = has1 ? idxb[base + 1] : p0;
        // ---- point 0
        float ax0 = pts[p0 * 3], ay0 = pts[p0 * 3 + 1], az0 = pts[p0 * 3 + 2];
        const float4* fp0 = (const float4*)(feat + (((size_t)p0) << 6) + ch0);
        float4 f00 = fp0[0], f01 = fp0[1], f02 = fp0[2], f03 = fp0[3];
        // ---- point 1
        float ax1 = pts[p1 * 3], ay1 = pts[p1 * 3 + 1], az1 = pts[p1 * 3 + 2];
        const float4* fp1 = (const float4*)(feat + (((size_t)p1) << 6) + ch0);
        float4 f10 = fp1[0], f11 = fp1[1], f12 = fp1[2], f13 = fp1[3];

        int lx, ly, lz; float fx, fy, fz;
        corner_setup(ax0, ay0, az0, lx, ly, lz, fx, fy, fz);
        int qx = lx - cx0, qy = ly - cy0, qz = lz - cz0;
        float wx = (cx == qx) ? (1.f - fx) : ((cx == qx + 1) ? fx : 0.f);
        float wy = (cy == qy) ? (1.f - fy) : ((cy == qy + 1) ? fy : 0.f);
        float wz = (cz == qz) ? (1.f - fz) : ((cz == qz + 1) ? fz : 0.f);
        float w0 = wx * wy * wz;

        corner_setup(ax1, ay1, az1, lx, ly, lz, fx, fy, fz);
        qx = lx - cx0; qy = ly - cy0; qz = lz - cz0;
        wx = (cx == qx) ? (1.f - fx) : ((cx == qx + 1) ? fx : 0.f);
        wy = (cy == qy) ? (1.f - fy) : ((cy == qy + 1) ? fy : 0.f);
        wz = (cz == qz) ? (1.f - fz) : ((cz == qz + 1) ? fz : 0.f);
        float w1 = has1 ? (wx * wy * wz) : 0.f;

        cwr += w0 + w1;
        acc[0]  += w0 * f00.x + w1 * f10.x;
        acc[1]  += w0 * f00.y + w1 * f10.y;
        acc[2]  += w0 * f00.z + w1 * f10.z;
        acc[3]  += w0 * f00.w + w1 * f10.w;
        acc[4]  += w0 * f01.x + w1 * f11.x;
        acc[5]  += w0 * f01.y + w1 * f11.y;
        acc[6]  += w0 * f01.z + w1 * f11.z;
        acc[7]  += w0 * f01.w + w1 * f11.w;
        acc[8]  += w0 * f02.x + w1 * f12.x;
        acc[9]  += w0 * f02.y + w1 * f12.y;
        acc[10] += w0 * f02.z + w1 * f12.z;
        acc[11] += w0 * f02.w + w1 * f12.w;
        acc[12] += w0 * f03.x + w1 * f13.x;
        acc[13] += w0 * f03.y + w1 * f13.y;
        acc[14] += w0 * f03.z + w1 * f13.z;
        acc[15] += w0 * f03.w + w1 * f13.w;
    }

    // transpose to LDS with rotation swizzle: addr(cell,ch) = cell*64 + ((ch+cell)&63)
#pragma unroll
    for (int k = 0; k < 16; ++k) {
        int ch = ch0 + k;
        accs[(lane << 6) + ((ch + lane) & 63)] = acc[k];
    }
    cws[lane] = cwr;                 // identical across waves (same list, same order)
    __syncthreads();

    // normalize + write + per-channel partial sums (lane = channel here)
    float s = 0.f, q = 0.f;
    for (int c = wv; c < 64; c += 4) {       // c = cell
        float v = accs[(c << 6) + ((lane + c) & 63)] / fmaxf(cws[c], 1e-8f);
        int cxx = cx0 + (c >> 4), cyy = cy0 + ((c >> 2) & 3), czz = cz0 + (c & 3);
        size_t flat = ((size_t)(b << 15)) + (size_t)((cxx << 10) | (cyy << 5) | czz);
        vox[(flat << 6) + lane] = v;
        s += v; q += v * v;
    }
    rs[tid] = s; rq[tid] = q;
    __syncthreads();
    if (tid < 64) {
        s = rs[tid] + rs[tid + 64] + rs[tid + 128] + rs[tid + 192];
        q = rq[tid] + rq[tid + 64] + rq[tid + 128] + rq[tid + 192];
        atomicAdd(&chsum[((b << 6) + tid) * 2], s);
        atomicAdd(&chsum[((b << 6) + tid) * 2 + 1], q);
    }
}

// ---------------- per-channel partial sums for GN2 (reads conv1 output)
__global__ __launch_bounds__(256) void norm_stats(const float* __restrict__ src,
                                                  float* __restrict__ chsum) {
    __shared__ float rs[256], rq[256];
    int b = blockIdx.y;
    int tid = threadIdx.x;
    int c = tid & 63, rsub = tid >> 6;
    size_t rowb = ((size_t)b << 15) + (size_t)blockIdx.x * 256;
    float s = 0.f, q = 0.f;
    for (int i = 0; i < 64; ++i) {
        size_t idx = ((rowb + rsub + i * 4) << 6) + c;
        float v = src[idx];
        s += v; q += v * v;
    }
    rs[tid] = s; rq[tid] = q;
    __syncthreads();
    if (tid < 64) {
        s = rs[tid] + rs[tid + 64] + rs[tid + 128] + rs[tid + 192];
        q = rq[tid] + rq[tid + 64] + rq[tid + 128] + rq[tid + 192];
        atomicAdd(&chsum[((b << 6) + tid) * 2], s);
        atomicAdd(&chsum[((b << 6) + tid) * 2 + 1], q);
    }
}

// ---------------- finalize GN stats: chsum[b][64][2] -> musr[b][32][2] (mu, rstd)
__global__ void gn_finalize(const float* __restrict__ chsum, float* __restrict__ musr) {
    int t = threadIdx.x;              // 256 = 8 b * 32 g
    int b = t >> 5, g = t & 31;
    float s = chsum[((b << 6) + 2 * g) * 2] + chsum[((b << 6) + 2 * g + 1) * 2];
    float q = chsum[((b << 6) + 2 * g) * 2 + 1] + chsum[((b << 6) + 2 * g + 1) * 2 + 1];
    float mu = s * (1.f / 65536.f);
    float var = q * (1.f / 65536.f) - mu * mu;
    musr[t * 2] = mu;
    musr[t * 2 + 1] = rsqrtf(var + 1e-5f);
}

// ---------------- GN apply + leaky -> bf16 hi/lo activation planes
__global__ __launch_bounds__(256) void gn_apply(const float* __restrict__ src,
                                                const float* __restrict__ musr,
                                                const float* __restrict__ gamma,
                                                const float* __restrict__ beta,
                                                unsigned short* __restrict__ hi,
                                                unsigned short* __restrict__ lo) {
    int i4 = blockIdx.x * 256 + threadIdx.x;     // B*R3*16
    int row = i4 >> 4;
    int b = row >> 15;
    int c0 = (i4 & 15) << 2;
    const float4 x = *(const float4*)(src + ((size_t)i4 << 2));
    float xs[4] = {x.x, x.y, x.z, x.w};
    unsigned short hs[4], ls[4];
#pragma unroll
    for (int j = 0; j < 4; ++j) {
        int c = c0 + j;
        int g = c >> 1;
        float mu = musr[((b << 5) + g) * 2];
        float rstd = musr[((b << 5) + g) * 2 + 1];
        float y = (xs[j] - mu) * rstd * gamma[c] + beta[c];
        y = leaky(y);
        hs[j] = f2bf(y);
        ls[j] = f2bf(y - bf2f(hs[j]));
    }
    ushort4 H; H.x = hs[0]; H.y = hs[1]; H.z = hs[2]; H.w = hs[3];
    ushort4 L; L.x = ls[0]; L.y = ls[1]; L.z = ls[2]; L.w = ls[3];
    *(ushort4*)(hi + ((size_t)i4 << 2)) = H;
    *(ushort4*)(lo + ((size_t)i4 << 2)) = L;
}

// ---------------- conv3d 3x3x3 SAME, 64->64ch, bf16 hi/lo 3-term MFMA
__global__ __launch_bounds__(256, 2) void conv3d_k(
        const unsigned short* __restrict__ Ah, const unsigned short* __restrict__ Al,
        const unsigned short* __restrict__ Wh, const unsigned short* __restrict__ Wl,
        const float* __restrict__ bias, const float* __restrict__ skip,
        float* __restrict__ out, const char* __restrict__ zp) {
    __shared__ __align__(16) unsigned short sAh[16384], sAl[16384], sWh[4096], sWl[4096]; // 80KB
    int tid = threadIdx.x;
    int lane = tid & 63, wave = tid >> 6;
    int wg = blockIdx.x;                       // 1024; XCD-swizzle: one batch per XCD
    int sw = (wg & 7) * 128 + (wg >> 3);
    int b = sw >> 7, t = sw & 127;
    int w0 = (t & 3) << 3, h0 = ((t >> 2) & 3) << 3, d0 = (t >> 4) << 2;

    f32x4 acc[4][4] = {};
    const char* AhB = (const char*)Ah;
    const char* AlB = (const char*)Al;
    const char* WhB = (const char*)Wh;
    const char* WlB = (const char*)Wl;

    for (int ko = 0; ko < 27; ++ko) {
        int di = ko / 9, rem = ko - di * 9, dj = rem / 3, dk = rem - dj * 3;
        __syncthreads();                       // all waves done reading previous tap
        // ---- stage A hi+lo
#pragma unroll
        for (int i = 0; i < 8; ++i) {
            int X = (i * 256 + tid) << 4;      // linear LDS byte
            int row = X >> 7;                  // voxel row (128B rows)
            int gran = ((X >> 4) & 7) ^ (row & 7);   // source pre-swizzle
            int d = row >> 6, h = (row >> 3) & 7, w = row & 7;
            int gd = d0 + d + di - 1, gh = h0 + h + dj - 1, gw = w0 + w + dk - 1;
            bool ok = ((unsigned)gd < 32u) & ((unsigned)gh < 32u) & ((unsigned)gw < 32u);
            size_t goff = ((((size_t)(b << 15)) +
                            (size_t)((gd << 10) + (gh << 5) + gw)) << 7) + (gran << 4);
            const char* gph = ok ? (AhB + goff) : (zp + (gran << 4));
            const char* gpl = ok ? (AlB + goff) : (zp + (gran << 4));
            int ldsoff = (i * 256 + (wave << 6)) << 4;   // wave-uniform base
            gload_lds16(gph, (char*)sAh + ldsoff);
            gload_lds16(gpl, (char*)sAl + ldsoff);
        }
        // ---- stage W hi+lo
#pragma unroll
        for (int i = 0; i < 2; ++i) {
            int X = (i * 256 + tid) << 4;
            int row = X >> 7;                  // cout row
            int gran = ((X >> 4) & 7) ^ (row & 7);
            size_t goff = ((size_t)((ko << 12) + (row << 6) + (gran << 3))) << 1;
            int ldsoff = (i * 256 + (wave << 6)) << 4;
            gload_lds16(WhB + goff, (char*)sWh + ldsoff);
            gload_lds16(WlB + goff, (char*)sWl + ldsoff);
        }
        __syncthreads();
        // ---- compute
#pragma unroll
        for (int kh = 0; kh < 2; ++kh) {
            bf16x8 a_h[4], a_l[4], b_h[4], b_l[4];
#pragma unroll
            for (int mf = 0; mf < 4; ++mf) {
                int arow = (wave << 6) + (mf << 4) + (lane & 15);
                int byteoff = (arow << 7) | ((((kh << 2) | (lane >> 4)) ^ (arow & 7)) << 4);
                a_h[mf] = *(const bf16x8*)((const char*)sAh + byteoff);
                a_l[mf] = *(const bf16x8*)((const char*)sAl + byteoff);
            }
#pragma unroll
            for (int nf = 0; nf < 4; ++nf) {
                int brow = (nf << 4) + (lane & 15);
                int byteoff = (brow << 7) | ((((kh << 2) | (lane >> 4)) ^ (brow & 7)) << 4);
                b_h[nf] = *(const bf16x8*)((const char*)sWh + byteoff);
                b_l[nf] = *(const bf16x8*)((const char*)sWl + byteoff);
            }
#pragma unroll
            for (int mf = 0; mf < 4; ++mf)
#pragma unroll
                for (int nf = 0; nf < 4; ++nf) {
                    acc[mf][nf] = __builtin_amdgcn_mfma_f32_16x16x32_bf16(a_h[mf], b_h[nf], acc[mf][nf], 0, 0, 0);
                    acc[mf][nf] = __builtin_amdgcn_mfma_f32_16x16x32_bf16(a_h[mf], b_l[nf], acc[mf][nf], 0, 0, 0);
                    acc[mf][nf] = __builtin_amdgcn_mfma_f32_16x16x32_bf16(a_l[mf], b_h[nf], acc[mf][nf], 0, 0, 0);
                }
        }
    }
    // ---- epilogue
#pragma unroll
    for (int mf = 0; mf < 4; ++mf) {
#pragma unroll
        for (int nf = 0; nf < 4; ++nf) {
            int co = (nf << 4) + (lane & 15);
            float bv = bias[co];
#pragma unroll
            for (int r = 0; r < 4; ++r) {
                int vrow = (wave << 6) + (mf << 4) + ((lane >> 4) << 2) + r;
                int d = vrow >> 6, h = (vrow >> 3) & 7, w = vrow & 7;
                size_t flat = ((size_t)(b << 15)) +
                              (size_t)(((d0 + d) << 10) + ((h0 + h) << 5) + (w0 + w));
                size_t oi = (flat << 6) + co;
                float v = acc[mf][nf][r] + bv;
                if (skip) v = (v + skip[oi]) * RSQRT2;
                out[oi] = v;
            }
        }
    }
}

// ---------------- point MLP: 3x (64x64 GEMM) via MFMA bf16 hi/lo, 256 pts/block
__global__ __launch_bounds__(256, 2) void point_mlp(
        const float* __restrict__ feat,
        const unsigned short* __restrict__ Mh, const unsigned short* __restrict__ Ml,
        const float* __restrict__ b0, const float* __restrict__ b1,
        const float* __restrict__ b2, float* __restrict__ pout) {
    __shared__ __align__(16) unsigned short sAh[16384], sAl[16384], sWh[4096], sWl[4096]; // 80KB
    int tid = threadIdx.x, lane = tid & 63, wave = tid >> 6;
    size_t pbase = (size_t)blockIdx.x << 8;

    // stage A: feat fp32 -> bf16 hi/lo, swizzled (rows = points, 128B rows)
    const float4* f4 = (const float4*)(feat + (pbase << 6));
#pragma unroll
    for (int j = 0; j < 16; ++j) {
        int fidx = j * 256 + tid;
        float4 v = f4[fidx];
        float vv[4] = {v.x, v.y, v.z, v.w};
        unsigned short hh[4], ll[4];
#pragma unroll
        for (int k = 0; k < 4; ++k) { hh[k] = f2bf(vv[k]); ll[k] = f2bf(vv[k] - bf2f(hh[k])); }
        ushort4 H; H.x = hh[0]; H.y = hh[1]; H.z = hh[2]; H.w = hh[3];
        ushort4 Lo; Lo.x = ll[0]; Lo.y = ll[1]; Lo.z = ll[2]; Lo.w = ll[3];
        int Xb = fidx << 3;                    // byte offset in bf16 A-plane
        int row = Xb >> 7;
        int dest = (row << 7) | ((((Xb >> 4) & 7) ^ (row & 7)) << 4) | (Xb & 8);
        *(ushort4*)((char*)sAh + dest) = H;
        *(ushort4*)((char*)sAl + dest) = Lo;
    }

    f32x4 f0[4][4];
#pragma unroll
    for (int L = 0; L < 3; ++L) {
        __syncthreads();                       // A/act writes visible; sW free
        // stage W layer L (pre-swizzled source, linear LDS dest)
#pragma unroll
        for (int i = 0; i < 2; ++i) {
            int X = (i * 256 + tid) << 4;
            int row = X >> 7;
            int gran = ((X >> 4) & 7) ^ (row & 7);
            size_t goff = ((size_t)((L << 12) + (row << 6) + (gran << 3))) << 1;
            int ldsoff = (i * 256 + (wave << 6)) << 4;
            gload_lds16((const char*)Mh + goff, (char*)sWh + ldsoff);
            gload_lds16((const char*)Ml + goff, (char*)sWl + ldsoff);
        }
        __syncthreads();
        f32x4 acc[4][4] = {};
#pragma unroll
        for (int kh = 0; kh < 2; ++kh) {
            bf16x8 a_h[4], a_l[4], b_h[4], b_l[4];
#pragma unroll
            for (int mf = 0; mf < 4; ++mf) {
                int arow = (wave << 6) + (mf << 4) + (lane & 15);
                int byteoff = (arow << 7) | ((((kh << 2) | (lane >> 4)) ^ (arow & 7)) << 4);
                a_h[mf] = *(const bf16x8*)((const char*)sAh + byteoff);
                a_l[mf] = *(const bf16x8*)((const char*)sAl + byteoff);
            }
#pragma unroll
            for (int nf = 0; nf < 4; ++nf) {
                int brow = (nf << 4) + (lane & 15);
                int byteoff = (brow << 7) | ((((kh << 2) | (lane >> 4)) ^ (brow & 7)) << 4);
                b_h[nf] = *(const bf16x8*)((const char*)sWh + byteoff);
                b_l[nf] = *(const bf16x8*)((const char*)sWl + byteoff);
            }
#pragma unroll
            for (int mf = 0; mf < 4; ++mf)
#pragma unroll
                for (int nf = 0; nf < 4; ++nf) {
                    acc[mf][nf] = __builtin_amdgcn_mfma_f32_16x16x32_bf16(a_h[mf], b_h[nf], acc[mf][nf], 0, 0, 0);
                    acc[mf][nf] = __builtin_amdgcn_mfma_f32_16x16x32_bf16(a_h[mf], b_l[nf], acc[mf][nf], 0, 0, 0);
                    acc[mf][nf] = __builtin_amdgcn_mfma_f32_16x16x32_bf16(a_l[mf], b_h[nf], acc[mf][nf], 0, 0, 0);
                }
        }
        const float* bp = (L == 0) ? b0 : (L == 1) ? b1 : b2;
        if (L < 2) {
            __syncthreads();                   // all waves done reading sA this layer
#pragma unroll
            for (int nf = 0; nf < 4; ++nf) {
                int col = (nf << 4) + (lane & 15);
                float bv = bp[col];
#pragma unroll
                for (int mf = 0; mf < 4; ++mf)
#pragma unroll
                    for (int r = 0; r < 4; ++r) {
                        float v = acc[mf][nf][r] + bv;
                        if (L == 0) f0[mf][nf][r] = v;
                        float a = leaky(v);
                        unsigned short h = f2bf(a);
                        unsigned short l = f2bf(a - bf2f(h));
                        int row = (wave << 6) + (mf << 4) + ((lane >> 4) << 2) + r;
                        int dest = (row << 7) | (((col >> 3) ^ (row & 7)) << 4) | ((col << 1) & 15);
                        *(unsigned short*)((char*)sAh + dest) = h;
                        *(unsigned short*)((char*)sAl + dest) = l;
                    }
            }
        } else {
#pragma unroll
            for (int nf = 0; nf < 4; ++nf) {
                int col = (nf << 4) + (lane & 15);
                float bv = bp[col];
#pragma unroll
                for (int mf = 0; mf < 4; ++mf)
#pragma unroll
                    for (int r = 0; r < 4; ++r) {
                        int row = (wave << 6) + (mf << 4) + ((lane >> 4) << 2) + r;
                        float v = (acc[mf][nf][r] + bv + f0[mf][nf][r]) * RSQRT2;
                        pout[((pbase + row) << 6) + col] = v;
                    }
            }
        }
    }
}

// ---------------- devoxelize gather + final combine (lean, high-occupancy)
__global__ __launch_bounds__(256, 8) void devox_combine(
        const float* __restrict__ pts, const float* __restrict__ pmlp,
        const float* __restrict__ grid, float* __restrict__ out) {
    __shared__ int   sFl[64][8];
    __shared__ float sWt[64][8];
    int tid = threadIdx.x;
    size_t pbase = (size_t)blockIdx.x << 6;
    int b = (int)(pbase >> 15);
    if (tid < 64) {
        const float* P = pts + (pbase + tid) * 3;
        int lx, ly, lz; float fx, fy, fz;
        corner_setup(P[0], P[1], P[2], lx, ly, lz, fx, fy, fz);
        int base3 = (lx << 10) + (ly << 5) + lz;
#pragma unroll
        for (int cr = 0; cr < 8; ++cr) {
            sFl[tid][cr] = base3 + (cr >> 2) * 1024 + ((cr >> 1) & 1) * 32 + (cr & 1);
            sWt[tid][cr] = ((cr & 4) ? fx : 1.f - fx) * ((cr & 2) ? fy : 1.f - fy)
                         * ((cr & 1) ? fz : 1.f - fz);
        }
    }
    __syncthreads();
    int c = tid & 63, wv = tid >> 6;
    const float* gb = grid + (((size_t)b) << 21);
#pragma unroll 4
    for (int i = 0; i < 16; ++i) {
        int p = (wv << 4) + i;                 // whole wave shares p -> LDS broadcast
        float dev = 0.f;
#pragma unroll
        for (int cr = 0; cr < 8; ++cr)
            dev += sWt[p][cr] * gb[(((size_t)sFl[p][cr]) << 6) + c];
        size_t oi = ((pbase + p) << 6) + c;
        out[oi] = (pmlp[oi] + dev) * RSQRT2;
    }
}

// ---------------- workspace layout (bytes)
constexpr size_t OFF_VOX  = 0;                           // f32 [8][32768][64] (normalized)
constexpr size_t OFF_GBUF = 67108864;                    // f32 [8][32768][64]
constexpr size_t OFF_AHI  = OFF_GBUF + 67108864;         // bf16 staging; later pmlp f32 (64MB)
constexpr size_t OFF_ALO  = OFF_AHI + 33554432;
constexpr size_t OFF_W1H  = OFF_ALO + 33554432;          // bf16 [27][64][64]
constexpr size_t OFF_W1L  = OFF_W1H + 262144;
constexpr size_t OFF_W2H  = OFF_W1L + 262144;
constexpr size_t OFF_W2L  = OFF_W2H + 262144;
constexpr size_t OFF_CS1  = OFF_W2L + 262144;            // f32 [8][64][2]
constexpr size_t OFF_CS2  = OFF_CS1 + 4096;
constexpr size_t OFF_MS1  = OFF_CS2 + 4096;              // f32 [8][32][2]
constexpr size_t OFF_MS2  = OFF_MS1 + 2048;
constexpr size_t OFF_BCNT = OFF_MS2 + 2048;              // int [4096]
constexpr size_t OFF_BSTA = OFF_BCNT + 16384;            // int [4097]
constexpr size_t OFF_BCUR = OFF_BSTA + 20480;            // int [4096]
constexpr size_t OFF_IDX  = OFF_BCUR + 16384;            // int [<=2097152] (8x worst case)
constexpr size_t OFF_ZP   = OFF_IDX + 8388608;           // 256B zeros
constexpr size_t OFF_MWH  = OFF_ZP + 256;                // bf16 [3][64][64]
constexpr size_t OFF_MWL  = OFF_MWH + 24576;
constexpr size_t OFF_END  = OFF_MWL + 24576;

extern "C" void kernel_launch(void* const* d_in, const int* in_sizes, int n_in,
                              void* d_out, int out_size, void* d_ws, size_t ws_size,
                              hipStream_t stream) {
    const float* points = (const float*)d_in[0];
    const float* feat   = (const float*)d_in[1];
    const float* w_pi = (const float*)d_in[2];
    const float* b_pi = (const float*)d_in[3];
    const float* w_p1 = (const float*)d_in[4];
    const float* b_p1 = (const float*)d_in[5];
    const float* w_p2 = (const float*)d_in[6];
    const float* b_p2 = (const float*)d_in[7];
    const float* g1   = (const float*)d_in[8];
    const float* be1  = (const float*)d_in[9];
    const float* w_c1 = (const float*)d_in[10];
    const float* b_c1 = (const float*)d_in[11];
    const float* g2   = (const float*)d_in[12];
    const float* be2  = (const float*)d_in[13];
    const float* w_c2 = (const float*)d_in[14];
    const float* b_c2 = (const float*)d_in[15];

    char* ws = (char*)d_ws;
    float* vox  = (float*)(ws + OFF_VOX);
    float* gbuf = (float*)(ws + OFF_GBUF);
    unsigned short* ahi = (unsigned short*)(ws + OFF_AHI);
    unsigned short* alo = (unsigned short*)(ws + OFF_ALO);
    float* pmlp = (float*)(ws + OFF_AHI);      // reuses ahi+alo after conv2
    unsigned short* w1h = (unsigned short*)(ws + OFF_W1H);
    unsigned short* w1l = (unsigned short*)(ws + OFF_W1L);
    unsigned short* w2h = (unsigned short*)(ws + OFF_W2H);
    unsigned short* w2l = (unsigned short*)(ws + OFF_W2L);
    float* cs1 = (float*)(ws + OFF_CS1);
    float* cs2 = (float*)(ws + OFF_CS2);
    float* ms1 = (float*)(ws + OFF_MS1);
    float* ms2 = (float*)(ws + OFF_MS2);
    int* bcnt = (int*)(ws + OFF_BCNT);
    int* bsta = (int*)(ws + OFF_BSTA);
    int* bcur = (int*)(ws + OFF_BCUR);
    int* idxb = (int*)(ws + OFF_IDX);
    char* zp  = ws + OFF_ZP;
    unsigned short* mwh = (unsigned short*)(ws + OFF_MWH);
    unsigned short* mwl = (unsigned short*)(ws + OFF_MWL);

    hipMemsetAsync(ws + OFF_CS1, 0, 12288, stream);
    hipMemsetAsync(ws + OFF_BCNT, 0, 16384, stream);
    hipMemsetAsync(ws + OFF_ZP, 0, 256, stream);

    wt_transform<<<432, 256, 0, stream>>>(w_c1, w1h, w1l);
    wt_transform<<<432, 256, 0, stream>>>(w_c2, w2h, w2l);
    mlp_wt<<<48, 256, 0, stream>>>(w_pi, w_p1, w_p2, mwh, mwl);

    bin_count<<<1024, 256, 0, stream>>>(points, bcnt);
    bin_scan<<<1, 256, 0, stream>>>(bcnt, bsta, bcur);
    bin_fill<<<1024, 256, 0, stream>>>(points, bcur, idxb);
    vox_accum<<<4096, 256, 0, stream>>>(points, feat, bsta, idxb, vox, cs1);

    gn_finalize<<<1, 256, 0, stream>>>(cs1, ms1);
    gn_apply<<<16384, 256, 0, stream>>>(vox, ms1, g1, be1, ahi, alo);
    conv3d_k<<<1024, 256, 0, stream>>>(ahi, alo, w1h, w1l, b_c1, nullptr, gbuf, zp);

    norm_stats<<<dim3(128, 8), 256, 0, stream>>>(gbuf, cs2);
    gn_finalize<<<1, 256, 0, stream>>>(cs2, ms2);
    gn_apply<<<16384, 256, 0, stream>>>(gbuf, ms2, g2, be2, ahi, alo);
    conv3d_k<<<1024, 256, 0, stream>>>(ahi, alo, w2h, w2l, b_c2, vox, gbuf, zp);

    point_mlp<<<1024, 256, 0, stream>>>(feat, mwh, mwl, b_pi, b_p1, b_p2, pmlp);
    devox_combine<<<4096, 256, 0, stream>>>(points, pmlp, gbuf, (float*)d_out);
}

// Round 6
// 948.551 us; speedup vs baseline: 1.5915x; 1.1090x over previous
//
#include <hip/hip_runtime.h>

// PointVoxelCNN fused pipeline for MI355X (gfx950).
// B=8, N=32768, C=Cin=64, R=32, G=32 (2 channels/group).
// Round 6: vox_accum v3 — bin_fill precomputes {packed cell|pid, fx,fy,fz} per
// entry (stored in the later-reused AHI region); vox_accum waves split the list
// 4-ways, each accumulating all 64 channels (f32x4 acc[16], pk-fma), weight
// computed once per entry; cross-wave rotation-swizzled LDS reduction epilogue.
// Conv / point branch unchanged from round 5.

#define RSQRT2 0.70710678118654752440f

typedef float f32x4 __attribute__((ext_vector_type(4)));
typedef __bf16 bf16x8 __attribute__((ext_vector_type(8)));

static __device__ __forceinline__ unsigned short f2bf(float x) {
    union { float f; unsigned u; } v; v.f = x;
    unsigned r = v.u + 0x7FFFu + ((v.u >> 16) & 1u);
    return (unsigned short)(r >> 16);
}
static __device__ __forceinline__ float bf2f(unsigned short b) {
    union { unsigned u; float f; } v; v.u = ((unsigned)b) << 16; return v.f;
}
static __device__ __forceinline__ float leaky(float x) { return x >= 0.f ? x : 0.01f * x; }

static __device__ __forceinline__ void gload_lds16(const void* g, void* l) {
    __builtin_amdgcn_global_load_lds(
        (const __attribute__((address_space(1))) unsigned int*)g,
        (__attribute__((address_space(3))) unsigned int*)l, 16, 0, 0);
}

static __device__ __forceinline__ void corner_setup(float px, float py, float pz,
        int& lx, int& ly, int& lz, float& fx, float& fy, float& fz) {
    float cx = fminf(fmaxf((px + 1.f) * 15.5f, 0.f), 31.f);
    float cy = fminf(fmaxf((py + 1.f) * 15.5f, 0.f), 31.f);
    float cz = fminf(fmaxf((pz + 1.f) * 15.5f, 0.f), 31.f);
    lx = (int)cx; if (lx > 30) lx = 30; fx = cx - (float)lx;
    ly = (int)cy; if (ly > 30) ly = 30; fy = cy - (float)ly;
    lz = (int)cz; if (lz > 30) lz = 30; fz = cz - (float)lz;
}

// ---------------- weight transform: w[O][I][27] f32 -> wt[ko][co][ci] bf16 hi/lo
__global__ __launch_bounds__(256) void wt_transform(const float* __restrict__ w,
                                                    unsigned short* __restrict__ hi,
                                                    unsigned short* __restrict__ lo) {
    int idx = blockIdx.x * 256 + threadIdx.x;    // 27*64*64 = 110592
    int ko = idx >> 12;
    int co = (idx >> 6) & 63;
    int ci = idx & 63;
    float v = w[(co * 64 + ci) * 27 + ko];
    unsigned short h = f2bf(v);
    hi[idx] = h;
    lo[idx] = f2bf(v - bf2f(h));
}

// ---------------- MLP weight transform: w[ci][co] f32 -> wm[L][co][ci] bf16 hi/lo
__global__ __launch_bounds__(256) void mlp_wt(const float* __restrict__ w0,
                                              const float* __restrict__ w1,
                                              const float* __restrict__ w2,
                                              unsigned short* __restrict__ hi,
                                              unsigned short* __restrict__ lo) {
    int idx = blockIdx.x * 256 + threadIdx.x;    // 48*256 = 12288
    int L = idx >> 12, rem = idx & 4095;
    int co = rem >> 6, ci = rem & 63;
    const float* s = (L == 0) ? w0 : (L == 1) ? w1 : w2;
    float v = s[ci * 64 + co];
    unsigned short h = f2bf(v);
    hi[idx] = h;
    lo[idx] = f2bf(v - bf2f(h));
}

// ---------------- voxelize pass 1: count (point -> all touched regions)
__global__ __launch_bounds__(256) void bin_count(const float* __restrict__ pts,
                                                 int* __restrict__ cnt) {
    int p = blockIdx.x * 256 + threadIdx.x;      // 262144
    int lx, ly, lz; float fx, fy, fz;
    corner_setup(pts[p * 3], pts[p * 3 + 1], pts[p * 3 + 2], lx, ly, lz, fx, fy, fz);
    int b = p >> 15;
    int rx = lx >> 2, ry = ly >> 2, rz = lz >> 2;
    int mx = (lx & 3) == 3, my = (ly & 3) == 3, mz = (lz & 3) == 3;
#pragma unroll
    for (int d = 0; d < 8; ++d) {
        int dx = d >> 2, dy = (d >> 1) & 1, dz = d & 1;
        if (dx <= mx && dy <= my && dz <= mz) {
            int bin = (b << 9) | ((rx + dx) << 6) | ((ry + dy) << 3) | (rz + dz);
            atomicAdd(&cnt[bin], 1);
        }
    }
}

// ---------------- voxelize pass 2: exclusive scan of 4096 bins (1 block)
__global__ __launch_bounds__(256) void bin_scan(const int* __restrict__ cnt,
                                                int* __restrict__ start,
                                                int* __restrict__ cursor) {
    __shared__ int part[256];
    int t = threadIdx.x;
    int local[16];
    int s = 0;
#pragma unroll
    for (int i = 0; i < 16; ++i) { local[i] = s; s += cnt[t * 16 + i]; }
    part[t] = s;
    __syncthreads();
    for (int off = 1; off < 256; off <<= 1) {
        int v = (t >= off) ? part[t - off] : 0;
        __syncthreads();
        part[t] += v;
        __syncthreads();
    }
    int base = (t == 0) ? 0 : part[t - 1];
#pragma unroll
    for (int i = 0; i < 16; ++i) {
        int v = base + local[i];
        start[t * 16 + i] = v;
        cursor[t * 16 + i] = v;
    }
    if (t == 255) start[4096] = part[255];
}

// ---------------- voxelize pass 3: scatter packed entries into regions
// entry: u32 {uz(3b)<<24 | uy<<21 | ux<<18 | pid(18b)}, u = (l&3) - 4d + 1 in [0,4]
// plus f3[entry] = {fx, fy, fz, 0} (region-independent fracs)
__global__ __launch_bounds__(256) void bin_fill(const float* __restrict__ pts,
                                                int* __restrict__ cursor,
                                                unsigned int* __restrict__ idxb,
                                                float4* __restrict__ f3) {
    int p = blockIdx.x * 256 + threadIdx.x;
    int lx, ly, lz; float fx, fy, fz;
    corner_setup(pts[p * 3], pts[p * 3 + 1], pts[p * 3 + 2], lx, ly, lz, fx, fy, fz);
    int b = p >> 15;
    int rx = lx >> 2, ry = ly >> 2, rz = lz >> 2;
    int mx = (lx & 3) == 3, my = (ly & 3) == 3, mz = (lz & 3) == 3;
    float4 fr; fr.x = fx; fr.y = fy; fr.z = fz; fr.w = 0.f;
#pragma unroll
    for (int d = 0; d < 8; ++d) {
        int dx = d >> 2, dy = (d >> 1) & 1, dz = d & 1;
        if (dx <= mx && dy <= my && dz <= mz) {
            int bin = (b << 9) | ((rx + dx) << 6) | ((ry + dy) << 3) | (rz + dz);
            int slot = atomicAdd(&cursor[bin], 1);
            unsigned ux = (unsigned)((lx & 3) - 4 * dx + 1);
            unsigned uy = (unsigned)((ly & 3) - 4 * dy + 1);
            unsigned uz = (unsigned)((lz & 3) - 4 * dz + 1);
            idxb[slot] = (unsigned)p | (ux << 18) | (uy << 21) | (uz << 24);
            f3[slot] = fr;
        }
    }
}

// ---------------- voxelize pass 4: list-split register accumulate
// block = 4x4x4 region; lane = cell; each wave processes 1/4 of the entry list
// accumulating ALL 64 channels (f32x4 acc[16], pk-fma). Weight computed once
// per entry. Cross-wave reduction via rotation-swizzled LDS slab.
__global__ __launch_bounds__(256) void vox_accum(const float* __restrict__ feat,
                                                 const int* __restrict__ start,
                                                 const unsigned int* __restrict__ idxb,
                                                 const float4* __restrict__ f3,
                                                 float* __restrict__ vox,
                                                 float* __restrict__ chsum) {
    __shared__ float slab[4096];     // [cell][ch] rotation-swizzled
    __shared__ float cws4[4][64];
    __shared__ float cwsum[64];
    __shared__ float rs[256], rq[256];
    int tid = threadIdx.x, lane = tid & 63, wv = tid >> 6;
    int gid = blockIdx.x;            // 4096 = b*512 + r3
    int b = gid >> 9, r3 = gid & 511;
    int rx = r3 >> 6, ry = (r3 >> 3) & 7, rz = r3 & 7;
    int cx0 = rx << 2, cy0 = ry << 2, cz0 = rz << 2;
    int cx = lane >> 4, cy = (lane >> 2) & 3, cz = lane & 3;   // this lane's cell

    f32x4 acc[16] = {};
    float cwr = 0.f;

    int s0 = start[gid], s1 = start[gid + 1];
    for (int e = s0 + wv; e < s1; e += 4) {
        unsigned pk = idxb[e];
        float4 fr = f3[e];
        int pid = __builtin_amdgcn_readfirstlane((int)(pk & 0x3FFFFu));
        int qx = (int)((pk >> 18) & 7u) - 1;
        int qy = (int)((pk >> 21) & 7u) - 1;
        int qz = (int)((pk >> 24) & 7u) - 1;
        float wx = (cx == qx) ? (1.f - fr.x) : ((cx == qx + 1) ? fr.x : 0.f);
        float wy = (cy == qy) ? (1.f - fr.y) : ((cy == qy + 1) ? fr.y : 0.f);
        float wz = (cz == qz) ? (1.f - fr.z) : ((cz == qz + 1) ? fr.z : 0.f);
        float w = wx * wy * wz;
        cwr += w;
        const f32x4* fp = (const f32x4*)(feat + ((size_t)pid << 6));
        f32x4 fa[8];
#pragma unroll
        for (int k = 0; k < 8; ++k) fa[k] = fp[k];
#pragma unroll
        for (int k = 0; k < 8; ++k) acc[k] += fa[k] * w;
#pragma unroll
        for (int k = 0; k < 8; ++k) fa[k] = fp[8 + k];
#pragma unroll
        for (int k = 0; k < 8; ++k) acc[8 + k] += fa[k] * w;
    }

    cws4[wv][lane] = cwr;
    // cross-wave reduction into rotation-swizzled slab (2-way banks = free)
#pragma unroll
    for (int ph = 0; ph < 4; ++ph) {
        if (wv == ph) {
#pragma unroll
            for (int k = 0; k < 64; ++k) {
                int addr = (lane << 6) + ((k + lane) & 63);
                float v = acc[k >> 2][k & 3];
                if (ph) v += slab[addr];
                slab[addr] = v;
            }
        }
        __syncthreads();
    }
    if (tid < 64)
        cwsum[tid] = cws4[0][tid] + cws4[1][tid] + cws4[2][tid] + cws4[3][tid];
    __syncthreads();

    // normalize + write + per-channel partial sums (lane = channel here)
    float s = 0.f, q = 0.f;
    for (int c = wv; c < 64; c += 4) {       // c = cell
        float v = slab[(c << 6) + ((lane + c) & 63)] / fmaxf(cwsum[c], 1e-8f);
        int cxx = cx0 + (c >> 4), cyy = cy0 + ((c >> 2) & 3), czz = cz0 + (c & 3);
        size_t flat = ((size_t)(b << 15)) + (size_t)((cxx << 10) | (cyy << 5) | czz);
        vox[(flat << 6) + lane] = v;
        s += v; q += v * v;
    }
    rs[tid] = s; rq[tid] = q;
    __syncthreads();
    if (tid < 64) {
        s = rs[tid] + rs[tid + 64] + rs[tid + 128] + rs[tid + 192];
        q = rq[tid] + rq[tid + 64] + rq[tid + 128] + rq[tid + 192];
        atomicAdd(&chsum[((b << 6) + tid) * 2], s);
        atomicAdd(&chsum[((b << 6) + tid) * 2 + 1], q);
    }
}

// ---------------- per-channel partial sums for GN2 (reads conv1 output)
__global__ __launch_bounds__(256) void norm_stats(const float* __restrict__ src,
                                                  float* __restrict__ chsum) {
    __shared__ float rs[256], rq[256];
    int b = blockIdx.y;
    int tid = threadIdx.x;
    int c = tid & 63, rsub = tid >> 6;
    size_t rowb = ((size_t)b << 15) + (size_t)blockIdx.x * 256;
    float s = 0.f, q = 0.f;
    for (int i = 0; i < 64; ++i) {
        size_t idx = ((rowb + rsub + i * 4) << 6) + c;
        float v = src[idx];
        s += v; q += v * v;
    }
    rs[tid] = s; rq[tid] = q;
    __syncthreads();
    if (tid < 64) {
        s = rs[tid] + rs[tid + 64] + rs[tid + 128] + rs[tid + 192];
        q = rq[tid] + rq[tid + 64] + rq[tid + 128] + rq[tid + 192];
        atomicAdd(&chsum[((b << 6) + tid) * 2], s);
        atomicAdd(&chsum[((b << 6) + tid) * 2 + 1], q);
    }
}

// ---------------- finalize GN stats: chsum[b][64][2] -> musr[b][32][2] (mu, rstd)
__global__ void gn_finalize(const float* __restrict__ chsum, float* __restrict__ musr) {
    int t = threadIdx.x;              // 256 = 8 b * 32 g
    int b = t >> 5, g = t & 31;
    float s = chsum[((b << 6) + 2 * g) * 2] + chsum[((b << 6) + 2 * g + 1) * 2];
    float q = chsum[((b << 6) + 2 * g) * 2 + 1] + chsum[((b << 6) + 2 * g + 1) * 2 + 1];
    float mu = s * (1.f / 65536.f);
    float var = q * (1.f / 65536.f) - mu * mu;
    musr[t * 2] = mu;
    musr[t * 2 + 1] = rsqrtf(var + 1e-5f);
}

// ---------------- GN apply + leaky -> bf16 hi/lo activation planes
__global__ __launch_bounds__(256) void gn_apply(const float* __restrict__ src,
                                                const float* __restrict__ musr,
                                                const float* __restrict__ gamma,
                                                const float* __restrict__ beta,
                                                unsigned short* __restrict__ hi,
                                                unsigned short* __restrict__ lo) {
    int i4 = blockIdx.x * 256 + threadIdx.x;     // B*R3*16
    int row = i4 >> 4;
    int b = row >> 15;
    int c0 = (i4 & 15) << 2;
    const float4 x = *(const float4*)(src + ((size_t)i4 << 2));
    float xs[4] = {x.x, x.y, x.z, x.w};
    unsigned short hs[4], ls[4];
#pragma unroll
    for (int j = 0; j < 4; ++j) {
        int c = c0 + j;
        int g = c >> 1;
        float mu = musr[((b << 5) + g) * 2];
        float rstd = musr[((b << 5) + g) * 2 + 1];
        float y = (xs[j] - mu) * rstd * gamma[c] + beta[c];
        y = leaky(y);
        hs[j] = f2bf(y);
        ls[j] = f2bf(y - bf2f(hs[j]));
    }
    ushort4 H; H.x = hs[0]; H.y = hs[1]; H.z = hs[2]; H.w = hs[3];
    ushort4 L; L.x = ls[0]; L.y = ls[1]; L.z = ls[2]; L.w = ls[3];
    *(ushort4*)(hi + ((size_t)i4 << 2)) = H;
    *(ushort4*)(lo + ((size_t)i4 << 2)) = L;
}

// ---------------- conv3d 3x3x3 SAME, 64->64ch, bf16 hi/lo 3-term MFMA
__global__ __launch_bounds__(256, 2) void conv3d_k(
        const unsigned short* __restrict__ Ah, const unsigned short* __restrict__ Al,
        const unsigned short* __restrict__ Wh, const unsigned short* __restrict__ Wl,
        const float* __restrict__ bias, const float* __restrict__ skip,
        float* __restrict__ out, const char* __restrict__ zp) {
    __shared__ __align__(16) unsigned short sAh[16384], sAl[16384], sWh[4096], sWl[4096]; // 80KB
    int tid = threadIdx.x;
    int lane = tid & 63, wave = tid >> 6;
    int wg = blockIdx.x;                       // 1024; XCD-swizzle: one batch per XCD
    int sw = (wg & 7) * 128 + (wg >> 3);
    int b = sw >> 7, t = sw & 127;
    int w0 = (t & 3) << 3, h0 = ((t >> 2) & 3) << 3, d0 = (t >> 4) << 2;

    f32x4 acc[4][4] = {};
    const char* AhB = (const char*)Ah;
    const char* AlB = (const char*)Al;
    const char* WhB = (const char*)Wh;
    const char* WlB = (const char*)Wl;

    for (int ko = 0; ko < 27; ++ko) {
        int di = ko / 9, rem = ko - di * 9, dj = rem / 3, dk = rem - dj * 3;
        __syncthreads();                       // all waves done reading previous tap
        // ---- stage A hi+lo
#pragma unroll
        for (int i = 0; i < 8; ++i) {
            int X = (i * 256 + tid) << 4;      // linear LDS byte
            int row = X >> 7;                  // voxel row (128B rows)
            int gran = ((X >> 4) & 7) ^ (row & 7);   // source pre-swizzle
            int d = row >> 6, h = (row >> 3) & 7, w = row & 7;
            int gd = d0 + d + di - 1, gh = h0 + h + dj - 1, gw = w0 + w + dk - 1;
            bool ok = ((unsigned)gd < 32u) & ((unsigned)gh < 32u) & ((unsigned)gw < 32u);
            size_t goff = ((((size_t)(b << 15)) +
                            (size_t)((gd << 10) + (gh << 5) + gw)) << 7) + (gran << 4);
            const char* gph = ok ? (AhB + goff) : (zp + (gran << 4));
            const char* gpl = ok ? (AlB + goff) : (zp + (gran << 4));
            int ldsoff = (i * 256 + (wave << 6)) << 4;   // wave-uniform base
            gload_lds16(gph, (char*)sAh + ldsoff);
            gload_lds16(gpl, (char*)sAl + ldsoff);
        }
        // ---- stage W hi+lo
#pragma unroll
        for (int i = 0; i < 2; ++i) {
            int X = (i * 256 + tid) << 4;
            int row = X >> 7;                  // cout row
            int gran = ((X >> 4) & 7) ^ (row & 7);
            size_t goff = ((size_t)((ko << 12) + (row << 6) + (gran << 3))) << 1;
            int ldsoff = (i * 256 + (wave << 6)) << 4;
            gload_lds16(WhB + goff, (char*)sWh + ldsoff);
            gload_lds16(WlB + goff, (char*)sWl + ldsoff);
        }
        __syncthreads();
        // ---- compute
#pragma unroll
        for (int kh = 0; kh < 2; ++kh) {
            bf16x8 a_h[4], a_l[4], b_h[4], b_l[4];
#pragma unroll
            for (int mf = 0; mf < 4; ++mf) {
                int arow = (wave << 6) + (mf << 4) + (lane & 15);
                int byteoff = (arow << 7) | ((((kh << 2) | (lane >> 4)) ^ (arow & 7)) << 4);
                a_h[mf] = *(const bf16x8*)((const char*)sAh + byteoff);
                a_l[mf] = *(const bf16x8*)((const char*)sAl + byteoff);
            }
#pragma unroll
            for (int nf = 0; nf < 4; ++nf) {
                int brow = (nf << 4) + (lane & 15);
                int byteoff = (brow << 7) | ((((kh << 2) | (lane >> 4)) ^ (brow & 7)) << 4);
                b_h[nf] = *(const bf16x8*)((const char*)sWh + byteoff);
                b_l[nf] = *(const bf16x8*)((const char*)sWl + byteoff);
            }
#pragma unroll
            for (int mf = 0; mf < 4; ++mf)
#pragma unroll
                for (int nf = 0; nf < 4; ++nf) {
                    acc[mf][nf] = __builtin_amdgcn_mfma_f32_16x16x32_bf16(a_h[mf], b_h[nf], acc[mf][nf], 0, 0, 0);
                    acc[mf][nf] = __builtin_amdgcn_mfma_f32_16x16x32_bf16(a_h[mf], b_l[nf], acc[mf][nf], 0, 0, 0);
                    acc[mf][nf] = __builtin_amdgcn_mfma_f32_16x16x32_bf16(a_l[mf], b_h[nf], acc[mf][nf], 0, 0, 0);
                }
        }
    }
    // ---- epilogue
#pragma unroll
    for (int mf = 0; mf < 4; ++mf) {
#pragma unroll
        for (int nf = 0; nf < 4; ++nf) {
            int co = (nf << 4) + (lane & 15);
            float bv = bias[co];
#pragma unroll
            for (int r = 0; r < 4; ++r) {
                int vrow = (wave << 6) + (mf << 4) + ((lane >> 4) << 2) + r;
                int d = vrow >> 6, h = (vrow >> 3) & 7, w = vrow & 7;
                size_t flat = ((size_t)(b << 15)) +
                              (size_t)(((d0 + d) << 10) + ((h0 + h) << 5) + (w0 + w));
                size_t oi = (flat << 6) + co;
                float v = acc[mf][nf][r] + bv;
                if (skip) v = (v + skip[oi]) * RSQRT2;
                out[oi] = v;
            }
        }
    }
}

// ---------------- point MLP: 3x (64x64 GEMM) via MFMA bf16 hi/lo, 256 pts/block
__global__ __launch_bounds__(256, 2) void point_mlp(
        const float* __restrict__ feat,
        const unsigned short* __restrict__ Mh, const unsigned short* __restrict__ Ml,
        const float* __restrict__ b0, const float* __restrict__ b1,
        const float* __restrict__ b2, float* __restrict__ pout) {
    __shared__ __align__(16) unsigned short sAh[16384], sAl[16384], sWh[4096], sWl[4096]; // 80KB
    int tid = threadIdx.x, lane = tid & 63, wave = tid >> 6;
    size_t pbase = (size_t)blockIdx.x << 8;

    // stage A: feat fp32 -> bf16 hi/lo, swizzled (rows = points, 128B rows)
    const float4* f4 = (const float4*)(feat + (pbase << 6));
#pragma unroll
    for (int j = 0; j < 16; ++j) {
        int fidx = j * 256 + tid;
        float4 v = f4[fidx];
        float vv[4] = {v.x, v.y, v.z, v.w};
        unsigned short hh[4], ll[4];
#pragma unroll
        for (int k = 0; k < 4; ++k) { hh[k] = f2bf(vv[k]); ll[k] = f2bf(vv[k] - bf2f(hh[k])); }
        ushort4 H; H.x = hh[0]; H.y = hh[1]; H.z = hh[2]; H.w = hh[3];
        ushort4 Lo; Lo.x = ll[0]; Lo.y = ll[1]; Lo.z = ll[2]; Lo.w = ll[3];
        int Xb = fidx << 3;                    // byte offset in bf16 A-plane
        int row = Xb >> 7;
        int dest = (row << 7) | ((((Xb >> 4) & 7) ^ (row & 7)) << 4) | (Xb & 8);
        *(ushort4*)((char*)sAh + dest) = H;
        *(ushort4*)((char*)sAl + dest) = Lo;
    }

    f32x4 f0[4][4];
#pragma unroll
    for (int L = 0; L < 3; ++L) {
        __syncthreads();                       // A/act writes visible; sW free
        // stage W layer L (pre-swizzled source, linear LDS dest)
#pragma unroll
        for (int i = 0; i < 2; ++i) {
            int X = (i * 256 + tid) << 4;
            int row = X >> 7;
            int gran = ((X >> 4) & 7) ^ (row & 7);
            size_t goff = ((size_t)((L << 12) + (row << 6) + (gran << 3))) << 1;
            int ldsoff = (i * 256 + (wave << 6)) << 4;
            gload_lds16((const char*)Mh + goff, (char*)sWh + ldsoff);
            gload_lds16((const char*)Ml + goff, (char*)sWl + ldsoff);
        }
        __syncthreads();
        f32x4 acc[4][4] = {};
#pragma unroll
        for (int kh = 0; kh < 2; ++kh) {
            bf16x8 a_h[4], a_l[4], b_h[4], b_l[4];
#pragma unroll
            for (int mf = 0; mf < 4; ++mf) {
                int arow = (wave << 6) + (mf << 4) + (lane & 15);
                int byteoff = (arow << 7) | ((((kh << 2) | (lane >> 4)) ^ (arow & 7)) << 4);
                a_h[mf] = *(const bf16x8*)((const char*)sAh + byteoff);
                a_l[mf] = *(const bf16x8*)((const char*)sAl + byteoff);
            }
#pragma unroll
            for (int nf = 0; nf < 4; ++nf) {
                int brow = (nf << 4) + (lane & 15);
                int byteoff = (brow << 7) | ((((kh << 2) | (lane >> 4)) ^ (brow & 7)) << 4);
                b_h[nf] = *(const bf16x8*)((const char*)sWh + byteoff);
                b_l[nf] = *(const bf16x8*)((const char*)sWl + byteoff);
            }
#pragma unroll
            for (int mf = 0; mf < 4; ++mf)
#pragma unroll
                for (int nf = 0; nf < 4; ++nf) {
                    acc[mf][nf] = __builtin_amdgcn_mfma_f32_16x16x32_bf16(a_h[mf], b_h[nf], acc[mf][nf], 0, 0, 0);
                    acc[mf][nf] = __builtin_amdgcn_mfma_f32_16x16x32_bf16(a_h[mf], b_l[nf], acc[mf][nf], 0, 0, 0);
                    acc[mf][nf] = __builtin_amdgcn_mfma_f32_16x16x32_bf16(a_l[mf], b_h[nf], acc[mf][nf], 0, 0, 0);
                }
        }
        const float* bp = (L == 0) ? b0 : (L == 1) ? b1 : b2;
        if (L < 2) {
            __syncthreads();                   // all waves done reading sA this layer
#pragma unroll
            for (int nf = 0; nf < 4; ++nf) {
                int col = (nf << 4) + (lane & 15);
                float bv = bp[col];
#pragma unroll
                for (int mf = 0; mf < 4; ++mf)
#pragma unroll
                    for (int r = 0; r < 4; ++r) {
                        float v = acc[mf][nf][r] + bv;
                        if (L == 0) f0[mf][nf][r] = v;
                        float a = leaky(v);
                        unsigned short h = f2bf(a);
                        unsigned short l = f2bf(a - bf2f(h));
                        int row = (wave << 6) + (mf << 4) + ((lane >> 4) << 2) + r;
                        int dest = (row << 7) | (((col >> 3) ^ (row & 7)) << 4) | ((col << 1) & 15);
                        *(unsigned short*)((char*)sAh + dest) = h;
                        *(unsigned short*)((char*)sAl + dest) = l;
                    }
            }
        } else {
#pragma unroll
            for (int nf = 0; nf < 4; ++nf) {
                int col = (nf << 4) + (lane & 15);
                float bv = bp[col];
#pragma unroll
                for (int mf = 0; mf < 4; ++mf)
#pragma unroll
                    for (int r = 0; r < 4; ++r) {
                        int row = (wave << 6) + (mf << 4) + ((lane >> 4) << 2) + r;
                        float v = (acc[mf][nf][r] + bv + f0[mf][nf][r]) * RSQRT2;
                        pout[((pbase + row) << 6) + col] = v;
                    }
            }
        }
    }
}

// ---------------- devoxelize gather + final combine (lean, high-occupancy)
__global__ __launch_bounds__(256, 8) void devox_combine(
        const float* __restrict__ pts, const float* __restrict__ pmlp,
        const float* __restrict__ grid, float* __restrict__ out) {
    __shared__ int   sFl[64][8];
    __shared__ float sWt[64][8];
    int tid = threadIdx.x;
    size_t pbase = (size_t)blockIdx.x << 6;
    int b = (int)(pbase >> 15);
    if (tid < 64) {
        const float* P = pts + (pbase + tid) * 3;
        int lx, ly, lz; float fx, fy, fz;
        corner_setup(P[0], P[1], P[2], lx, ly, lz, fx, fy, fz);
        int base3 = (lx << 10) + (ly << 5) + lz;
#pragma unroll
        for (int cr = 0; cr < 8; ++cr) {
            sFl[tid][cr] = base3 + (cr >> 2) * 1024 + ((cr >> 1) & 1) * 32 + (cr & 1);
            sWt[tid][cr] = ((cr & 4) ? fx : 1.f - fx) * ((cr & 2) ? fy : 1.f - fy)
                         * ((cr & 1) ? fz : 1.f - fz);
        }
    }
    __syncthreads();
    int c = tid & 63, wv = tid >> 6;
    const float* gb = grid + (((size_t)b) << 21);
#pragma unroll 4
    for (int i = 0; i < 16; ++i) {
        int p = (wv << 4) + i;                 // whole wave shares p -> LDS broadcast
        float dev = 0.f;
#pragma unroll
        for (int cr = 0; cr < 8; ++cr)
            dev += sWt[p][cr] * gb[(((size_t)sFl[p][cr]) << 6) + c];
        size_t oi = ((pbase + p) << 6) + c;
        out[oi] = (pmlp[oi] + dev) * RSQRT2;
    }
}

// ---------------- workspace layout (bytes)
constexpr size_t OFF_VOX  = 0;                           // f32 [8][32768][64] (normalized)
constexpr size_t OFF_GBUF = 67108864;                    // f32 [8][32768][64]
constexpr size_t OFF_AHI  = OFF_GBUF + 67108864;         // f3 entries; bf16 staging; pmlp f32
constexpr size_t OFF_ALO  = OFF_AHI + 33554432;
constexpr size_t OFF_W1H  = OFF_ALO + 33554432;          // bf16 [27][64][64]
constexpr size_t OFF_W1L  = OFF_W1H + 262144;
constexpr size_t OFF_W2H  = OFF_W1L + 262144;
constexpr size_t OFF_W2L  = OFF_W2H + 262144;
constexpr size_t OFF_CS1  = OFF_W2L + 262144;            // f32 [8][64][2]
constexpr size_t OFF_CS2  = OFF_CS1 + 4096;
constexpr size_t OFF_MS1  = OFF_CS2 + 4096;              // f32 [8][32][2]
constexpr size_t OFF_MS2  = OFF_MS1 + 2048;
constexpr size_t OFF_BCNT = OFF_MS2 + 2048;              // int [4096]
constexpr size_t OFF_BSTA = OFF_BCNT + 16384;            // int [4097]
constexpr size_t OFF_BCUR = OFF_BSTA + 20480;            // int [4096]
constexpr size_t OFF_IDX  = OFF_BCUR + 16384;            // u32 [<=2097152] (8x worst case)
constexpr size_t OFF_ZP   = OFF_IDX + 8388608;           // 256B zeros
constexpr size_t OFF_MWH  = OFF_ZP + 256;                // bf16 [3][64][64]
constexpr size_t OFF_MWL  = OFF_MWH + 24576;
constexpr size_t OFF_END  = OFF_MWL + 24576;

extern "C" void kernel_launch(void* const* d_in, const int* in_sizes, int n_in,
                              void* d_out, int out_size, void* d_ws, size_t ws_size,
                              hipStream_t stream) {
    const float* points = (const float*)d_in[0];
    const float* feat   = (const float*)d_in[1];
    const float* w_pi = (const float*)d_in[2];
    const float* b_pi = (const float*)d_in[3];
    const float* w_p1 = (const float*)d_in[4];
    const float* b_p1 = (const float*)d_in[5];
    const float* w_p2 = (const float*)d_in[6];
    const float* b_p2 = (const float*)d_in[7];
    const float* g1   = (const float*)d_in[8];
    const float* be1  = (const float*)d_in[9];
    const float* w_c1 = (const float*)d_in[10];
    const float* b_c1 = (const float*)d_in[11];
    const float* g2   = (const float*)d_in[12];
    const float* be2  = (const float*)d_in[13];
    const float* w_c2 = (const float*)d_in[14];
    const float* b_c2 = (const float*)d_in[15];

    char* ws = (char*)d_ws;
    float* vox  = (float*)(ws + OFF_VOX);
    float* gbuf = (float*)(ws + OFF_GBUF);
    unsigned short* ahi = (unsigned short*)(ws + OFF_AHI);
    unsigned short* alo = (unsigned short*)(ws + OFF_ALO);
    float4* f3  = (float4*)(ws + OFF_AHI);     // entry fracs; region free until gn_apply
    float* pmlp = (float*)(ws + OFF_AHI);      // reuses ahi+alo after conv2
    unsigned short* w1h = (unsigned short*)(ws + OFF_W1H);
    unsigned short* w1l = (unsigned short*)(ws + OFF_W1L);
    unsigned short* w2h = (unsigned short*)(ws + OFF_W2H);
    unsigned short* w2l = (unsigned short*)(ws + OFF_W2L);
    float* cs1 = (float*)(ws + OFF_CS1);
    float* cs2 = (float*)(ws + OFF_CS2);
    float* ms1 = (float*)(ws + OFF_MS1);
    float* ms2 = (float*)(ws + OFF_MS2);
    int* bcnt = (int*)(ws + OFF_BCNT);
    int* bsta = (int*)(ws + OFF_BSTA);
    int* bcur = (int*)(ws + OFF_BCUR);
    unsigned int* idxb = (unsigned int*)(ws + OFF_IDX);
    char* zp  = ws + OFF_ZP;
    unsigned short* mwh = (unsigned short*)(ws + OFF_MWH);
    unsigned short* mwl = (unsigned short*)(ws + OFF_MWL);

    hipMemsetAsync(ws + OFF_CS1, 0, 12288, stream);
    hipMemsetAsync(ws + OFF_BCNT, 0, 16384, stream);
    hipMemsetAsync(ws + OFF_ZP, 0, 256, stream);

    wt_transform<<<432, 256, 0, stream>>>(w_c1, w1h, w1l);
    wt_transform<<<432, 256, 0, stream>>>(w_c2, w2h, w2l);
    mlp_wt<<<48, 256, 0, stream>>>(w_pi, w_p1, w_p2, mwh, mwl);

    bin_count<<<1024, 256, 0, stream>>>(points, bcnt);
    bin_scan<<<1, 256, 0, stream>>>(bcnt, bsta, bcur);
    bin_fill<<<1024, 256, 0, stream>>>(points, bcur, idxb, f3);
    vox_accum<<<4096, 256, 0, stream>>>(feat, bsta, idxb, f3, vox, cs1);

    gn_finalize<<<1, 256, 0, stream>>>(cs1, ms1);
    gn_apply<<<16384, 256, 0, stream>>>(vox, ms1, g1, be1, ahi, alo);
    conv3d_k<<<1024, 256, 0, stream>>>(ahi, alo, w1h, w1l, b_c1, nullptr, gbuf, zp);

    norm_stats<<<dim3(128, 8), 256, 0, stream>>>(gbuf, cs2);
    gn_finalize<<<1, 256, 0, stream>>>(cs2, ms2);
    gn_apply<<<16384, 256, 0, stream>>>(gbuf, ms2, g2, be2, ahi, alo);
    conv3d_k<<<1024, 256, 0, stream>>>(ahi, alo, w2h, w2l, b_c2, vox, gbuf, zp);

    point_mlp<<<1024, 256, 0, stream>>>(feat, mwh, mwl, b_pi, b_p1, b_p2, pmlp);
    devox_combine<<<4096, 256, 0, stream>>>(points, pmlp, gbuf, (float*)d_out);
}

// Round 7
// 933.780 us; speedup vs baseline: 1.6167x; 1.0158x over previous
//
#include <hip/hip_runtime.h>

// PointVoxelCNN fused pipeline for MI355X (gfx950).
// B=8, N=32768, C=Cin=64, R=32, G=32 (2 channels/group).
// Round 7: vox_accum v4 — the region accumulation is a GEMM:
//   out[64 cells][64 ch] = sum_e W[cell][e] * F[e][ch],  K = entries (~125).
// Per 64-entry chunk: coalesced feat loads + per-lane weight compute ->
// bf16 hi/lo XOR-swizzled LDS tiles -> 3-term MFMA, acc in registers.
// No atomics, no uniform-load latency chain, 8x less VALU.
// Conv / point branch / binning unchanged from round 6.

#define RSQRT2 0.70710678118654752440f

typedef float f32x4 __attribute__((ext_vector_type(4)));
typedef __bf16 bf16x8 __attribute__((ext_vector_type(8)));
typedef unsigned short u16x8 __attribute__((ext_vector_type(8)));

static __device__ __forceinline__ unsigned short f2bf(float x) {
    union { float f; unsigned u; } v; v.f = x;
    unsigned r = v.u + 0x7FFFu + ((v.u >> 16) & 1u);
    return (unsigned short)(r >> 16);
}
static __device__ __forceinline__ float bf2f(unsigned short b) {
    union { unsigned u; float f; } v; v.u = ((unsigned)b) << 16; return v.f;
}
static __device__ __forceinline__ float leaky(float x) { return x >= 0.f ? x : 0.01f * x; }

static __device__ __forceinline__ void gload_lds16(const void* g, void* l) {
    __builtin_amdgcn_global_load_lds(
        (const __attribute__((address_space(1))) unsigned int*)g,
        (__attribute__((address_space(3))) unsigned int*)l, 16, 0, 0);
}

static __device__ __forceinline__ void corner_setup(float px, float py, float pz,
        int& lx, int& ly, int& lz, float& fx, float& fy, float& fz) {
    float cx = fminf(fmaxf((px + 1.f) * 15.5f, 0.f), 31.f);
    float cy = fminf(fmaxf((py + 1.f) * 15.5f, 0.f), 31.f);
    float cz = fminf(fmaxf((pz + 1.f) * 15.5f, 0.f), 31.f);
    lx = (int)cx; if (lx > 30) lx = 30; fx = cx - (float)lx;
    ly = (int)cy; if (ly > 30) ly = 30; fy = cy - (float)ly;
    lz = (int)cz; if (lz > 30) lz = 30; fz = cz - (float)lz;
}

// ---------------- weight transform: w[O][I][27] f32 -> wt[ko][co][ci] bf16 hi/lo
__global__ __launch_bounds__(256) void wt_transform(const float* __restrict__ w,
                                                    unsigned short* __restrict__ hi,
                                                    unsigned short* __restrict__ lo) {
    int idx = blockIdx.x * 256 + threadIdx.x;    // 27*64*64 = 110592
    int ko = idx >> 12;
    int co = (idx >> 6) & 63;
    int ci = idx & 63;
    float v = w[(co * 64 + ci) * 27 + ko];
    unsigned short h = f2bf(v);
    hi[idx] = h;
    lo[idx] = f2bf(v - bf2f(h));
}

// ---------------- MLP weight transform: w[ci][co] f32 -> wm[L][co][ci] bf16 hi/lo
__global__ __launch_bounds__(256) void mlp_wt(const float* __restrict__ w0,
                                              const float* __restrict__ w1,
                                              const float* __restrict__ w2,
                                              unsigned short* __restrict__ hi,
                                              unsigned short* __restrict__ lo) {
    int idx = blockIdx.x * 256 + threadIdx.x;    // 48*256 = 12288
    int L = idx >> 12, rem = idx & 4095;
    int co = rem >> 6, ci = rem & 63;
    const float* s = (L == 0) ? w0 : (L == 1) ? w1 : w2;
    float v = s[ci * 64 + co];
    unsigned short h = f2bf(v);
    hi[idx] = h;
    lo[idx] = f2bf(v - bf2f(h));
}

// ---------------- voxelize pass 1: count (point -> all touched regions)
__global__ __launch_bounds__(256) void bin_count(const float* __restrict__ pts,
                                                 int* __restrict__ cnt) {
    int p = blockIdx.x * 256 + threadIdx.x;      // 262144
    int lx, ly, lz; float fx, fy, fz;
    corner_setup(pts[p * 3], pts[p * 3 + 1], pts[p * 3 + 2], lx, ly, lz, fx, fy, fz);
    int b = p >> 15;
    int rx = lx >> 2, ry = ly >> 2, rz = lz >> 2;
    int mx = (lx & 3) == 3, my = (ly & 3) == 3, mz = (lz & 3) == 3;
#pragma unroll
    for (int d = 0; d < 8; ++d) {
        int dx = d >> 2, dy = (d >> 1) & 1, dz = d & 1;
        if (dx <= mx && dy <= my && dz <= mz) {
            int bin = (b << 9) | ((rx + dx) << 6) | ((ry + dy) << 3) | (rz + dz);
            atomicAdd(&cnt[bin], 1);
        }
    }
}

// ---------------- voxelize pass 2: exclusive scan of 4096 bins (1 block)
__global__ __launch_bounds__(256) void bin_scan(const int* __restrict__ cnt,
                                                int* __restrict__ start,
                                                int* __restrict__ cursor) {
    __shared__ int part[256];
    int t = threadIdx.x;
    int local[16];
    int s = 0;
#pragma unroll
    for (int i = 0; i < 16; ++i) { local[i] = s; s += cnt[t * 16 + i]; }
    part[t] = s;
    __syncthreads();
    for (int off = 1; off < 256; off <<= 1) {
        int v = (t >= off) ? part[t - off] : 0;
        __syncthreads();
        part[t] += v;
        __syncthreads();
    }
    int base = (t == 0) ? 0 : part[t - 1];
#pragma unroll
    for (int i = 0; i < 16; ++i) {
        int v = base + local[i];
        start[t * 16 + i] = v;
        cursor[t * 16 + i] = v;
    }
    if (t == 255) start[4096] = part[255];
}

// ---------------- voxelize pass 3: scatter packed entries into regions
// entry: u32 {uz(3b)<<24 | uy<<21 | ux<<18 | pid(18b)}, u = (l&3) - 4d + 1 in [0,4]
// plus f3[entry] = {fx, fy, fz, 0}
__global__ __launch_bounds__(256) void bin_fill(const float* __restrict__ pts,
                                                int* __restrict__ cursor,
                                                unsigned int* __restrict__ idxb,
                                                float4* __restrict__ f3) {
    int p = blockIdx.x * 256 + threadIdx.x;
    int lx, ly, lz; float fx, fy, fz;
    corner_setup(pts[p * 3], pts[p * 3 + 1], pts[p * 3 + 2], lx, ly, lz, fx, fy, fz);
    int b = p >> 15;
    int rx = lx >> 2, ry = ly >> 2, rz = lz >> 2;
    int mx = (lx & 3) == 3, my = (ly & 3) == 3, mz = (lz & 3) == 3;
    float4 fr; fr.x = fx; fr.y = fy; fr.z = fz; fr.w = 0.f;
#pragma unroll
    for (int d = 0; d < 8; ++d) {
        int dx = d >> 2, dy = (d >> 1) & 1, dz = d & 1;
        if (dx <= mx && dy <= my && dz <= mz) {
            int bin = (b << 9) | ((rx + dx) << 6) | ((ry + dy) << 3) | (rz + dz);
            int slot = atomicAdd(&cursor[bin], 1);
            unsigned ux = (unsigned)((lx & 3) - 4 * dx + 1);
            unsigned uy = (unsigned)((ly & 3) - 4 * dy + 1);
            unsigned uz = (unsigned)((lz & 3) - 4 * dz + 1);
            idxb[slot] = (unsigned)p | (ux << 18) | (uy << 21) | (uz << 24);
            f3[slot] = fr;
        }
    }
}

// ---------------- voxelize pass 4: MFMA region-GEMM accumulate
// out[64 cells][64 ch] = sum_e W[cell][e] * F[e][ch].  Per 64-entry chunk:
// wave wv stages F (coalesced, lane=ch) and W (lane=cell weights) for entries
// wv*16..+15 into bf16 hi/lo XOR-swizzled LDS tiles, then 3-term MFMA.
__global__ __launch_bounds__(256) void vox_accum(const float* __restrict__ feat,
                                                 const int* __restrict__ start,
                                                 const unsigned int* __restrict__ idxb,
                                                 const float4* __restrict__ f3,
                                                 float* __restrict__ vox,
                                                 float* __restrict__ chsum) {
    __shared__ __align__(16) unsigned short Fh[4096], Fl[4096], Wh[4096], Wl[4096]; // 32KB
    __shared__ float slab[4096];     // 16KB, rotation-swizzled [cell][ch]
    __shared__ float cws4[4][64];
    __shared__ float cwsum[64];
    __shared__ float rs[256], rq[256];
    int tid = threadIdx.x, lane = tid & 63, wv = tid >> 6;
    int gid = blockIdx.x;            // 4096 = b*512 + r3
    int b = gid >> 9, r3 = gid & 511;
    int rx = r3 >> 6, ry = (r3 >> 3) & 7, rz = r3 & 7;
    int cx0 = rx << 2, cy0 = ry << 2, cz0 = rz << 2;
    int cx = lane >> 4, cy = (lane >> 2) & 3, cz = lane & 3;   // lane as cell

    f32x4 acc[4] = {};               // D[ch=wv*16.. ][cell 0..63], 4 nf frags
    float cwr = 0.f;

    int s0 = start[gid], s1 = start[gid + 1];
    int nch = (s1 - s0 + 63) >> 6;
    for (int c = 0; c < nch; ++c) {
        float vals[16], wgt[16];
        int ebase = s0 + (c << 6) + (wv << 4);
#pragma unroll
        for (int j = 0; j < 16; ++j) {
            int eg = ebase + j;
            int ee = (eg < s1) ? eg : s0;
            unsigned pk = idxb[ee];
            float4 fr = f3[ee];
            int pid = (int)(pk & 0x3FFFFu);
            vals[j] = feat[((size_t)pid << 6) + lane];        // coalesced 256B
            int qx = (int)((pk >> 18) & 7u) - 1;
            int qy = (int)((pk >> 21) & 7u) - 1;
            int qz = (int)((pk >> 24) & 7u) - 1;
            float wx = (cx == qx) ? (1.f - fr.x) : ((cx == qx + 1) ? fr.x : 0.f);
            float wy = (cy == qy) ? (1.f - fr.y) : ((cy == qy + 1) ? fr.y : 0.f);
            float wz = (cz == qz) ? (1.f - fr.z) : ((cz == qz + 1) ? fr.z : 0.f);
            float w = wx * wy * wz;
            if (eg >= s1) w = 0.f;
            wgt[j] = w;
            cwr += w;
        }
        // convert to bf16 hi/lo and write swizzled tiles (rows 128B = 64 entries)
#pragma unroll
        for (int g = 0; g < 2; ++g) {
            u16x8 FH, FL, WH, WL;
#pragma unroll
            for (int j = 0; j < 8; ++j) {
                float v = vals[g * 8 + j];
                unsigned short h = f2bf(v);
                FH[j] = h; FL[j] = f2bf(v - bf2f(h));
                float w = wgt[g * 8 + j];
                unsigned short h2 = f2bf(w);
                WH[j] = h2; WL[j] = f2bf(w - bf2f(h2));
            }
            int gran = (wv << 1) | g;                          // 16B granule 0..7
            int dst = (lane << 7) | ((gran ^ (lane & 7)) << 4);
            *(u16x8*)((char*)Fh + dst) = FH;                  // row = channel
            *(u16x8*)((char*)Fl + dst) = FL;
            *(u16x8*)((char*)Wh + dst) = WH;                  // row = cell
            *(u16x8*)((char*)Wl + dst) = WL;
        }
        __syncthreads();
        // 3-term MFMA: D[ch][cell] += F * W
#pragma unroll
        for (int kh = 0; kh < 2; ++kh) {
            int ks = (kh << 2) | (lane >> 4);
            int arow = (wv << 4) + (lane & 15);
            int aoff = (arow << 7) | ((ks ^ (arow & 7)) << 4);
            bf16x8 ah = *(const bf16x8*)((const char*)Fh + aoff);
            bf16x8 al = *(const bf16x8*)((const char*)Fl + aoff);
#pragma unroll
            for (int nf = 0; nf < 4; ++nf) {
                int brow = (nf << 4) + (lane & 15);
                int boff = (brow << 7) | ((ks ^ (brow & 7)) << 4);
                bf16x8 bh = *(const bf16x8*)((const char*)Wh + boff);
                bf16x8 bl = *(const bf16x8*)((const char*)Wl + boff);
                acc[nf] = __builtin_amdgcn_mfma_f32_16x16x32_bf16(ah, bh, acc[nf], 0, 0, 0);
                acc[nf] = __builtin_amdgcn_mfma_f32_16x16x32_bf16(ah, bl, acc[nf], 0, 0, 0);
                acc[nf] = __builtin_amdgcn_mfma_f32_16x16x32_bf16(al, bh, acc[nf], 0, 0, 0);
            }
        }
        __syncthreads();
    }

    cws4[wv][lane] = cwr;
    // D -> rotation-swizzled slab: lane holds ch = wv*16+(lane>>4)*4+r, cell = nf*16+(lane&15)
#pragma unroll
    for (int nf = 0; nf < 4; ++nf) {
        int cell = (nf << 4) + (lane & 15);
#pragma unroll
        for (int r = 0; r < 4; ++r) {
            int ch = (wv << 4) + ((lane >> 4) << 2) + r;
            slab[(cell << 6) + ((ch + cell) & 63)] = acc[nf][r];
        }
    }
    __syncthreads();
    if (tid < 64)
        cwsum[tid] = cws4[0][tid] + cws4[1][tid] + cws4[2][tid] + cws4[3][tid];
    __syncthreads();

    // normalize + write + per-channel partial sums (lane = channel here)
    float s = 0.f, q = 0.f;
    for (int c = wv; c < 64; c += 4) {       // c = cell
        float v = slab[(c << 6) + ((lane + c) & 63)] / fmaxf(cwsum[c], 1e-8f);
        int cxx = cx0 + (c >> 4), cyy = cy0 + ((c >> 2) & 3), czz = cz0 + (c & 3);
        size_t flat = ((size_t)(b << 15)) + (size_t)((cxx << 10) | (cyy << 5) | czz);
        vox[(flat << 6) + lane] = v;
        s += v; q += v * v;
    }
    rs[tid] = s; rq[tid] = q;
    __syncthreads();
    if (tid < 64) {
        s = rs[tid] + rs[tid + 64] + rs[tid + 128] + rs[tid + 192];
        q = rq[tid] + rq[tid + 64] + rq[tid + 128] + rq[tid + 192];
        atomicAdd(&chsum[((b << 6) + tid) * 2], s);
        atomicAdd(&chsum[((b << 6) + tid) * 2 + 1], q);
    }
}

// ---------------- per-channel partial sums for GN2 (reads conv1 output)
__global__ __launch_bounds__(256) void norm_stats(const float* __restrict__ src,
                                                  float* __restrict__ chsum) {
    __shared__ float rs[256], rq[256];
    int b = blockIdx.y;
    int tid = threadIdx.x;
    int c = tid & 63, rsub = tid >> 6;
    size_t rowb = ((size_t)b << 15) + (size_t)blockIdx.x * 256;
    float s = 0.f, q = 0.f;
    for (int i = 0; i < 64; ++i) {
        size_t idx = ((rowb + rsub + i * 4) << 6) + c;
        float v = src[idx];
        s += v; q += v * v;
    }
    rs[tid] = s; rq[tid] = q;
    __syncthreads();
    if (tid < 64) {
        s = rs[tid] + rs[tid + 64] + rs[tid + 128] + rs[tid + 192];
        q = rq[tid] + rq[tid + 64] + rq[tid + 128] + rq[tid + 192];
        atomicAdd(&chsum[((b << 6) + tid) * 2], s);
        atomicAdd(&chsum[((b << 6) + tid) * 2 + 1], q);
    }
}

// ---------------- finalize GN stats: chsum[b][64][2] -> musr[b][32][2] (mu, rstd)
__global__ void gn_finalize(const float* __restrict__ chsum, float* __restrict__ musr) {
    int t = threadIdx.x;              // 256 = 8 b * 32 g
    int b = t >> 5, g = t & 31;
    float s = chsum[((b << 6) + 2 * g) * 2] + chsum[((b << 6) + 2 * g + 1) * 2];
    float q = chsum[((b << 6) + 2 * g) * 2 + 1] + chsum[((b << 6) + 2 * g + 1) * 2 + 1];
    float mu = s * (1.f / 65536.f);
    float var = q * (1.f / 65536.f) - mu * mu;
    musr[t * 2] = mu;
    musr[t * 2 + 1] = rsqrtf(var + 1e-5f);
}

// ---------------- GN apply + leaky -> bf16 hi/lo activation planes
__global__ __launch_bounds__(256) void gn_apply(const float* __restrict__ src,
                                                const float* __restrict__ musr,
                                                const float* __restrict__ gamma,
                                                const float* __restrict__ beta,
                                                unsigned short* __restrict__ hi,
                                                unsigned short* __restrict__ lo) {
    int i4 = blockIdx.x * 256 + threadIdx.x;     // B*R3*16
    int row = i4 >> 4;
    int b = row >> 15;
    int c0 = (i4 & 15) << 2;
    const float4 x = *(const float4*)(src + ((size_t)i4 << 2));
    float xs[4] = {x.x, x.y, x.z, x.w};
    unsigned short hs[4], ls[4];
#pragma unroll
    for (int j = 0; j < 4; ++j) {
        int c = c0 + j;
        int g = c >> 1;
        float mu = musr[((b << 5) + g) * 2];
        float rstd = musr[((b << 5) + g) * 2 + 1];
        float y = (xs[j] - mu) * rstd * gamma[c] + beta[c];
        y = leaky(y);
        hs[j] = f2bf(y);
        ls[j] = f2bf(y - bf2f(hs[j]));
    }
    ushort4 H; H.x = hs[0]; H.y = hs[1]; H.z = hs[2]; H.w = hs[3];
    ushort4 L; L.x = ls[0]; L.y = ls[1]; L.z = ls[2]; L.w = ls[3];
    *(ushort4*)(hi + ((size_t)i4 << 2)) = H;
    *(ushort4*)(lo + ((size_t)i4 << 2)) = L;
}

// ---------------- conv3d 3x3x3 SAME, 64->64ch, bf16 hi/lo 3-term MFMA
__global__ __launch_bounds__(256, 2) void conv3d_k(
        const unsigned short* __restrict__ Ah, const unsigned short* __restrict__ Al,
        const unsigned short* __restrict__ Wh, const unsigned short* __restrict__ Wl,
        const float* __restrict__ bias, const float* __restrict__ skip,
        float* __restrict__ out, const char* __restrict__ zp) {
    __shared__ __align__(16) unsigned short sAh[16384], sAl[16384], sWh[4096], sWl[4096]; // 80KB
    int tid = threadIdx.x;
    int lane = tid & 63, wave = tid >> 6;
    int wg = blockIdx.x;                       // 1024; XCD-swizzle: one batch per XCD
    int sw = (wg & 7) * 128 + (wg >> 3);
    int b = sw >> 7, t = sw & 127;
    int w0 = (t & 3) << 3, h0 = ((t >> 2) & 3) << 3, d0 = (t >> 4) << 2;

    f32x4 acc[4][4] = {};
    const char* AhB = (const char*)Ah;
    const char* AlB = (const char*)Al;
    const char* WhB = (const char*)Wh;
    const char* WlB = (const char*)Wl;

    for (int ko = 0; ko < 27; ++ko) {
        int di = ko / 9, rem = ko - di * 9, dj = rem / 3, dk = rem - dj * 3;
        __syncthreads();                       // all waves done reading previous tap
        // ---- stage A hi+lo
#pragma unroll
        for (int i = 0; i < 8; ++i) {
            int X = (i * 256 + tid) << 4;      // linear LDS byte
            int row = X >> 7;                  // voxel row (128B rows)
            int gran = ((X >> 4) & 7) ^ (row & 7);   // source pre-swizzle
            int d = row >> 6, h = (row >> 3) & 7, w = row & 7;
            int gd = d0 + d + di - 1, gh = h0 + h + dj - 1, gw = w0 + w + dk - 1;
            bool ok = ((unsigned)gd < 32u) & ((unsigned)gh < 32u) & ((unsigned)gw < 32u);
            size_t goff = ((((size_t)(b << 15)) +
                            (size_t)((gd << 10) + (gh << 5) + gw)) << 7) + (gran << 4);
            const char* gph = ok ? (AhB + goff) : (zp + (gran << 4));
            const char* gpl = ok ? (AlB + goff) : (zp + (gran << 4));
            int ldsoff = (i * 256 + (wave << 6)) << 4;   // wave-uniform base
            gload_lds16(gph, (char*)sAh + ldsoff);
            gload_lds16(gpl, (char*)sAl + ldsoff);
        }
        // ---- stage W hi+lo
#pragma unroll
        for (int i = 0; i < 2; ++i) {
            int X = (i * 256 + tid) << 4;
            int row = X >> 7;                  // cout row
            int gran = ((X >> 4) & 7) ^ (row & 7);
            size_t goff = ((size_t)((ko << 12) + (row << 6) + (gran << 3))) << 1;
            int ldsoff = (i * 256 + (wave << 6)) << 4;
            gload_lds16(WhB + goff, (char*)sWh + ldsoff);
            gload_lds16(WlB + goff, (char*)sWl + ldsoff);
        }
        __syncthreads();
        // ---- compute
#pragma unroll
        for (int kh = 0; kh < 2; ++kh) {
            bf16x8 a_h[4], a_l[4], b_h[4], b_l[4];
#pragma unroll
            for (int mf = 0; mf < 4; ++mf) {
                int arow = (wave << 6) + (mf << 4) + (lane & 15);
                int byteoff = (arow << 7) | ((((kh << 2) | (lane >> 4)) ^ (arow & 7)) << 4);
                a_h[mf] = *(const bf16x8*)((const char*)sAh + byteoff);
                a_l[mf] = *(const bf16x8*)((const char*)sAl + byteoff);
            }
#pragma unroll
            for (int nf = 0; nf < 4; ++nf) {
                int brow = (nf << 4) + (lane & 15);
                int byteoff = (brow << 7) | ((((kh << 2) | (lane >> 4)) ^ (brow & 7)) << 4);
                b_h[nf] = *(const bf16x8*)((const char*)sWh + byteoff);
                b_l[nf] = *(const bf16x8*)((const char*)sWl + byteoff);
            }
#pragma unroll
            for (int mf = 0; mf < 4; ++mf)
#pragma unroll
                for (int nf = 0; nf < 4; ++nf) {
                    acc[mf][nf] = __builtin_amdgcn_mfma_f32_16x16x32_bf16(a_h[mf], b_h[nf], acc[mf][nf], 0, 0, 0);
                    acc[mf][nf] = __builtin_amdgcn_mfma_f32_16x16x32_bf16(a_h[mf], b_l[nf], acc[mf][nf], 0, 0, 0);
                    acc[mf][nf] = __builtin_amdgcn_mfma_f32_16x16x32_bf16(a_l[mf], b_h[nf], acc[mf][nf], 0, 0, 0);
                }
        }
    }
    // ---- epilogue
#pragma unroll
    for (int mf = 0; mf < 4; ++mf) {
#pragma unroll
        for (int nf = 0; nf < 4; ++nf) {
            int co = (nf << 4) + (lane & 15);
            float bv = bias[co];
#pragma unroll
            for (int r = 0; r < 4; ++r) {
                int vrow = (wave << 6) + (mf << 4) + ((lane >> 4) << 2) + r;
                int d = vrow >> 6, h = (vrow >> 3) & 7, w = vrow & 7;
                size_t flat = ((size_t)(b << 15)) +
                              (size_t)(((d0 + d) << 10) + ((h0 + h) << 5) + (w0 + w));
                size_t oi = (flat << 6) + co;
                float v = acc[mf][nf][r] + bv;
                if (skip) v = (v + skip[oi]) * RSQRT2;
                out[oi] = v;
            }
        }
    }
}

// ---------------- point MLP: 3x (64x64 GEMM) via MFMA bf16 hi/lo, 256 pts/block
__global__ __launch_bounds__(256, 2) void point_mlp(
        const float* __restrict__ feat,
        const unsigned short* __restrict__ Mh, const unsigned short* __restrict__ Ml,
        const float* __restrict__ b0, const float* __restrict__ b1,
        const float* __restrict__ b2, float* __restrict__ pout) {
    __shared__ __align__(16) unsigned short sAh[16384], sAl[16384], sWh[4096], sWl[4096]; // 80KB
    int tid = threadIdx.x, lane = tid & 63, wave = tid >> 6;
    size_t pbase = (size_t)blockIdx.x << 8;

    // stage A: feat fp32 -> bf16 hi/lo, swizzled (rows = points, 128B rows)
    const float4* f4 = (const float4*)(feat + (pbase << 6));
#pragma unroll
    for (int j = 0; j < 16; ++j) {
        int fidx = j * 256 + tid;
        float4 v = f4[fidx];
        float vv[4] = {v.x, v.y, v.z, v.w};
        unsigned short hh[4], ll[4];
#pragma unroll
        for (int k = 0; k < 4; ++k) { hh[k] = f2bf(vv[k]); ll[k] = f2bf(vv[k] - bf2f(hh[k])); }
        ushort4 H; H.x = hh[0]; H.y = hh[1]; H.z = hh[2]; H.w = hh[3];
        ushort4 Lo; Lo.x = ll[0]; Lo.y = ll[1]; Lo.z = ll[2]; Lo.w = ll[3];
        int Xb = fidx << 3;                    // byte offset in bf16 A-plane
        int row = Xb >> 7;
        int dest = (row << 7) | ((((Xb >> 4) & 7) ^ (row & 7)) << 4) | (Xb & 8);
        *(ushort4*)((char*)sAh + dest) = H;
        *(ushort4*)((char*)sAl + dest) = Lo;
    }

    f32x4 f0[4][4];
#pragma unroll
    for (int L = 0; L < 3; ++L) {
        __syncthreads();                       // A/act writes visible; sW free
        // stage W layer L (pre-swizzled source, linear LDS dest)
#pragma unroll
        for (int i = 0; i < 2; ++i) {
            int X = (i * 256 + tid) << 4;
            int row = X >> 7;
            int gran = ((X >> 4) & 7) ^ (row & 7);
            size_t goff = ((size_t)((L << 12) + (row << 6) + (gran << 3))) << 1;
            int ldsoff = (i * 256 + (wave << 6)) << 4;
            gload_lds16((const char*)Mh + goff, (char*)sWh + ldsoff);
            gload_lds16((const char*)Ml + goff, (char*)sWl + ldsoff);
        }
        __syncthreads();
        f32x4 acc[4][4] = {};
#pragma unroll
        for (int kh = 0; kh < 2; ++kh) {
            bf16x8 a_h[4], a_l[4], b_h[4], b_l[4];
#pragma unroll
            for (int mf = 0; mf < 4; ++mf) {
                int arow = (wave << 6) + (mf << 4) + (lane & 15);
                int byteoff = (arow << 7) | ((((kh << 2) | (lane >> 4)) ^ (arow & 7)) << 4);
                a_h[mf] = *(const bf16x8*)((const char*)sAh + byteoff);
                a_l[mf] = *(const bf16x8*)((const char*)sAl + byteoff);
            }
#pragma unroll
            for (int nf = 0; nf < 4; ++nf) {
                int brow = (nf << 4) + (lane & 15);
                int byteoff = (brow << 7) | ((((kh << 2) | (lane >> 4)) ^ (brow & 7)) << 4);
                b_h[nf] = *(const bf16x8*)((const char*)sWh + byteoff);
                b_l[nf] = *(const bf16x8*)((const char*)sWl + byteoff);
            }
#pragma unroll
            for (int mf = 0; mf < 4; ++mf)
#pragma unroll
                for (int nf = 0; nf < 4; ++nf) {
                    acc[mf][nf] = __builtin_amdgcn_mfma_f32_16x16x32_bf16(a_h[mf], b_h[nf], acc[mf][nf], 0, 0, 0);
                    acc[mf][nf] = __builtin_amdgcn_mfma_f32_16x16x32_bf16(a_h[mf], b_l[nf], acc[mf][nf], 0, 0, 0);
                    acc[mf][nf] = __builtin_amdgcn_mfma_f32_16x16x32_bf16(a_l[mf], b_h[nf], acc[mf][nf], 0, 0, 0);
                }
        }
        const float* bp = (L == 0) ? b0 : (L == 1) ? b1 : b2;
        if (L < 2) {
            __syncthreads();                   // all waves done reading sA this layer
#pragma unroll
            for (int nf = 0; nf < 4; ++nf) {
                int col = (nf << 4) + (lane & 15);
                float bv = bp[col];
#pragma unroll
                for (int mf = 0; mf < 4; ++mf)
#pragma unroll
                    for (int r = 0; r < 4; ++r) {
                        float v = acc[mf][nf][r] + bv;
                        if (L == 0) f0[mf][nf][r] = v;
                        float a = leaky(v);
                        unsigned short h = f2bf(a);
                        unsigned short l = f2bf(a - bf2f(h));
                        int row = (wave << 6) + (mf << 4) + ((lane >> 4) << 2) + r;
                        int dest = (row << 7) | (((col >> 3) ^ (row & 7)) << 4) | ((col << 1) & 15);
                        *(unsigned short*)((char*)sAh + dest) = h;
                        *(unsigned short*)((char*)sAl + dest) = l;
                    }
            }
        } else {
#pragma unroll
            for (int nf = 0; nf < 4; ++nf) {
                int col = (nf << 4) + (lane & 15);
                float bv = bp[col];
#pragma unroll
                for (int mf = 0; mf < 4; ++mf)
#pragma unroll
                    for (int r = 0; r < 4; ++r) {
                        int row = (wave << 6) + (mf << 4) + ((lane >> 4) << 2) + r;
                        float v = (acc[mf][nf][r] + bv + f0[mf][nf][r]) * RSQRT2;
                        pout[((pbase + row) << 6) + col] = v;
                    }
            }
        }
    }
}

// ---------------- devoxelize gather + final combine (lean, high-occupancy)
__global__ __launch_bounds__(256, 8) void devox_combine(
        const float* __restrict__ pts, const float* __restrict__ pmlp,
        const float* __restrict__ grid, float* __restrict__ out) {
    __shared__ int   sFl[64][8];
    __shared__ float sWt[64][8];
    int tid = threadIdx.x;
    size_t pbase = (size_t)blockIdx.x << 6;
    int b = (int)(pbase >> 15);
    if (tid < 64) {
        const float* P = pts + (pbase + tid) * 3;
        int lx, ly, lz; float fx, fy, fz;
        corner_setup(P[0], P[1], P[2], lx, ly, lz, fx, fy, fz);
        int base3 = (lx << 10) + (ly << 5) + lz;
#pragma unroll
        for (int cr = 0; cr < 8; ++cr) {
            sFl[tid][cr] = base3 + (cr >> 2) * 1024 + ((cr >> 1) & 1) * 32 + (cr & 1);
            sWt[tid][cr] = ((cr & 4) ? fx : 1.f - fx) * ((cr & 2) ? fy : 1.f - fy)
                         * ((cr & 1) ? fz : 1.f - fz);
        }
    }
    __syncthreads();
    int c = tid & 63, wv = tid >> 6;
    const float* gb = grid + (((size_t)b) << 21);
#pragma unroll 4
    for (int i = 0; i < 16; ++i) {
        int p = (wv << 4) + i;                 // whole wave shares p -> LDS broadcast
        float dev = 0.f;
#pragma unroll
        for (int cr = 0; cr < 8; ++cr)
            dev += sWt[p][cr] * gb[(((size_t)sFl[p][cr]) << 6) + c];
        size_t oi = ((pbase + p) << 6) + c;
        out[oi] = (pmlp[oi] + dev) * RSQRT2;
    }
}

// ---------------- workspace layout (bytes)
constexpr size_t OFF_VOX  = 0;                           // f32 [8][32768][64] (normalized)
constexpr size_t OFF_GBUF = 67108864;                    // f32 [8][32768][64]
constexpr size_t OFF_AHI  = OFF_GBUF + 67108864;         // f3 entries; bf16 staging; pmlp f32
constexpr size_t OFF_ALO  = OFF_AHI + 33554432;
constexpr size_t OFF_W1H  = OFF_ALO + 33554432;          // bf16 [27][64][64]
constexpr size_t OFF_W1L  = OFF_W1H + 262144;
constexpr size_t OFF_W2H  = OFF_W1L + 262144;
constexpr size_t OFF_W2L  = OFF_W2H + 262144;
constexpr size_t OFF_CS1  = OFF_W2L + 262144;            // f32 [8][64][2]
constexpr size_t OFF_CS2  = OFF_CS1 + 4096;
constexpr size_t OFF_MS1  = OFF_CS2 + 4096;              // f32 [8][32][2]
constexpr size_t OFF_MS2  = OFF_MS1 + 2048;
constexpr size_t OFF_BCNT = OFF_MS2 + 2048;              // int [4096]
constexpr size_t OFF_BSTA = OFF_BCNT + 16384;            // int [4097]
constexpr size_t OFF_BCUR = OFF_BSTA + 20480;            // int [4096]
constexpr size_t OFF_IDX  = OFF_BCUR + 16384;            // u32 [<=2097152] (8x worst case)
constexpr size_t OFF_ZP   = OFF_IDX + 8388608;           // 256B zeros
constexpr size_t OFF_MWH  = OFF_ZP + 256;                // bf16 [3][64][64]
constexpr size_t OFF_MWL  = OFF_MWH + 24576;
constexpr size_t OFF_END  = OFF_MWL + 24576;

extern "C" void kernel_launch(void* const* d_in, const int* in_sizes, int n_in,
                              void* d_out, int out_size, void* d_ws, size_t ws_size,
                              hipStream_t stream) {
    const float* points = (const float*)d_in[0];
    const float* feat   = (const float*)d_in[1];
    const float* w_pi = (const float*)d_in[2];
    const float* b_pi = (const float*)d_in[3];
    const float* w_p1 = (const float*)d_in[4];
    const float* b_p1 = (const float*)d_in[5];
    const float* w_p2 = (const float*)d_in[6];
    const float* b_p2 = (const float*)d_in[7];
    const float* g1   = (const float*)d_in[8];
    const float* be1  = (const float*)d_in[9];
    const float* w_c1 = (const float*)d_in[10];
    const float* b_c1 = (const float*)d_in[11];
    const float* g2   = (const float*)d_in[12];
    const float* be2  = (const float*)d_in[13];
    const float* w_c2 = (const float*)d_in[14];
    const float* b_c2 = (const float*)d_in[15];

    char* ws = (char*)d_ws;
    float* vox  = (float*)(ws + OFF_VOX);
    float* gbuf = (float*)(ws + OFF_GBUF);
    unsigned short* ahi = (unsigned short*)(ws + OFF_AHI);
    unsigned short* alo = (unsigned short*)(ws + OFF_ALO);
    float4* f3  = (float4*)(ws + OFF_AHI);     // entry fracs; region free until gn_apply
    float* pmlp = (float*)(ws + OFF_AHI);      // reuses ahi+alo after conv2
    unsigned short* w1h = (unsigned short*)(ws + OFF_W1H);
    unsigned short* w1l = (unsigned short*)(ws + OFF_W1L);
    unsigned short* w2h = (unsigned short*)(ws + OFF_W2H);
    unsigned short* w2l = (unsigned short*)(ws + OFF_W2L);
    float* cs1 = (float*)(ws + OFF_CS1);
    float* cs2 = (float*)(ws + OFF_CS2);
    float* ms1 = (float*)(ws + OFF_MS1);
    float* ms2 = (float*)(ws + OFF_MS2);
    int* bcnt = (int*)(ws + OFF_BCNT);
    int* bsta = (int*)(ws + OFF_BSTA);
    int* bcur = (int*)(ws + OFF_BCUR);
    unsigned int* idxb = (unsigned int*)(ws + OFF_IDX);
    char* zp  = ws + OFF_ZP;
    unsigned short* mwh = (unsigned short*)(ws + OFF_MWH);
    unsigned short* mwl = (unsigned short*)(ws + OFF_MWL);

    hipMemsetAsync(ws + OFF_CS1, 0, 12288, stream);
    hipMemsetAsync(ws + OFF_BCNT, 0, 16384, stream);
    hipMemsetAsync(ws + OFF_ZP, 0, 256, stream);

    wt_transform<<<432, 256, 0, stream>>>(w_c1, w1h, w1l);
    wt_transform<<<432, 256, 0, stream>>>(w_c2, w2h, w2l);
    mlp_wt<<<48, 256, 0, stream>>>(w_pi, w_p1, w_p2, mwh, mwl);

    bin_count<<<1024, 256, 0, stream>>>(points, bcnt);
    bin_scan<<<1, 256, 0, stream>>>(bcnt, bsta, bcur);
    bin_fill<<<1024, 256, 0, stream>>>(points, bcur, idxb, f3);
    vox_accum<<<4096, 256, 0, stream>>>(feat, bsta, idxb, f3, vox, cs1);

    gn_finalize<<<1, 256, 0, stream>>>(cs1, ms1);
    gn_apply<<<16384, 256, 0, stream>>>(vox, ms1, g1, be1, ahi, alo);
    conv3d_k<<<1024, 256, 0, stream>>>(ahi, alo, w1h, w1l, b_c1, nullptr, gbuf, zp);

    norm_stats<<<dim3(128, 8), 256, 0, stream>>>(gbuf, cs2);
    gn_finalize<<<1, 256, 0, stream>>>(cs2, ms2);
    gn_apply<<<16384, 256, 0, stream>>>(gbuf, ms2, g2, be2, ahi, alo);
    conv3d_k<<<1024, 256, 0, stream>>>(ahi, alo, w2h, w2l, b_c2, vox, gbuf, zp);

    point_mlp<<<1024, 256, 0, stream>>>(feat, mwh, mwl, b_pi, b_p1, b_p2, pmlp);
    devox_combine<<<4096, 256, 0, stream>>>(points, pmlp, gbuf, (float*)d_out);
}